// Round 21
// baseline (280.677 us; speedup 1.0000x reference)
//
#include <hip/hip_runtime.h>
#include <hip/hip_bf16.h>
#include <stdint.h>

// ---- problem constants ----
static constexpr int HW = 4096;     // 64*64
static constexpr int Cc = 256;
static constexpr int Gg = 32;
static constexpr float EPSV = 1e-6f;
static constexpr float QSCALE = 0.0625f * 1.44269504f;   // c^-0.5 * log2(e): softmax in exp2 domain

typedef __attribute__((ext_vector_type(8))) short bf8_t;     // 8 bf16 (4 VGPR)
typedef __attribute__((ext_vector_type(4))) float f4_t;      // 16x16 mfma acc
typedef __attribute__((ext_vector_type(16))) float f32x16;   // 32x32 mfma acc

__device__ __forceinline__ ushort f2bf(float x) {
    union { float f; uint32_t u; } v; v.f = x;
    uint32_t r = v.u + 0x7FFFu + ((v.u >> 16) & 1u);
    return (ushort)(r >> 16);
}
__device__ __forceinline__ float bf2f(ushort u) {
    union { uint32_t u; float f; } v; v.u = ((uint32_t)u) << 16;
    return v.f;
}
__device__ __forceinline__ uint32_t cvtpk(float lo, float hi_) {
    uint32_t r;
    asm volatile("v_cvt_pk_bf16_f32 %0, %1, %2" : "=v"(r) : "v"(lo), "v"(hi_));
    return r;
}
__device__ __forceinline__ float fexp2(float x) {   // raw v_exp_f32
    float r;
    asm("v_exp_f32 %0, %1" : "=v"(r) : "v"(x));
    return r;
}

// async global->LDS DMA, 16B per lane; lds dest is wave-uniform base (+lane*16 by HW)
__device__ __forceinline__ void gload16(const void* g, void* l) {
    __builtin_amdgcn_global_load_lds((const __attribute__((address_space(1))) void*)g,
                                     (__attribute__((address_space(3))) void*)l, 16, 0, 0);
}

// ---------------- prep: GN partial sums (blocks 0..511) + weight transpose (blocks 512..767) --
// wT[which][d][c] = bf16(w[c][d])
__global__ void prep_kernel(const float* __restrict__ x, float* __restrict__ psum,
                            float* __restrict__ psumsq,
                            const float* __restrict__ wq, const float* __restrict__ wk,
                            const float* __restrict__ wv, const float* __restrict__ wp,
                            ushort* __restrict__ wT) {
    int bx = blockIdx.x;
    if (bx < 512) {
        int slice = bx & 63;
        int b = bx >> 6;
        int c = threadIdx.x;
        const float* xp = x + ((size_t)b * HW + (size_t)slice * 64) * Cc + c;
        float s = 0.f, sq = 0.f;
        for (int p = 0; p < 64; ++p) { float v = xp[(size_t)p * Cc]; s += v; sq += v * v; }
        for (int m = 1; m < 8; m <<= 1) { s += __shfl_xor(s, m); sq += __shfl_xor(sq, m); }
        if ((c & 7) == 0) {
            int g = c >> 3;
            psum[(b * Gg + g) * 64 + slice] = s;
            psumsq[(b * Gg + g) * 64 + slice] = sq;
        }
    } else {
        int base = (bx - 512) * 1024 + threadIdx.x * 4;   // 4 consecutive c, same d
        int which = base >> 16;
        const float* w = which == 0 ? wq : which == 1 ? wk : which == 2 ? wv : wp;
        int rem = base & 65535;
        int d = rem >> 8, c = rem & 255;
        ushort4 o;
        o.x = f2bf(w[(c + 0) * 256 + d]);
        o.y = f2bf(w[(c + 1) * 256 + d]);
        o.z = f2bf(w[(c + 2) * 256 + d]);
        o.w = f2bf(w[(c + 3) * 256 + d]);
        *(ushort4*)&wT[which * 65536 + d * 256 + c] = o;
    }
}

__global__ void gn_stats(const float* __restrict__ psum, const float* __restrict__ psumsq,
                         float* __restrict__ stats) {
    int t = threadIdx.x;  // 256 = b*32+g
    float s = 0.f, sq = 0.f;
    for (int i = 0; i < 64; ++i) { s += psum[t * 64 + i]; sq += psumsq[t * 64 + i]; }
    float mean = s * (1.0f / 32768.0f);
    float var = sq * (1.0f / 32768.0f) - mean * mean;
    stats[t * 2] = mean;
    stats[t * 2 + 1] = rsqrtf(var + EPSV);
}

// ---------------- fused GN-normalize + QKV GEMM (wave = 64 rows x 64 cols) ----------------
__global__ __launch_bounds__(256) void qkv_gn(const float* __restrict__ x, const float* __restrict__ stats,
                                              const float* __restrict__ gs, const float* __restrict__ gb,
                                              const ushort* __restrict__ wT,
                                              const float* __restrict__ bq, const float* __restrict__ bk,
                                              const float* __restrict__ bv,
                                              ushort* __restrict__ q, ushort* __restrict__ k,
                                              ushort* __restrict__ vT) {
    int lane = threadIdx.x & 63, wvi = threadIdx.x >> 6;
    int lq = lane & 15, lg = lane >> 4;
    int nf0 = wvi * 4;                  // wave's 4 col-tiles (64 cols)
    int m0b = blockIdx.x * 64;          // block's 64 rows (shared by all 4 waves)

    bf8_t a[4][8];
#pragma unroll
    for (int tt = 0; tt < 4; ++tt) {
        int row = m0b + tt * 16 + lq;
        int batch = row >> 12;
        const float* xr = x + (size_t)row * 256;
#pragma unroll
        for (int ks = 0; ks < 8; ++ks) {
            int c0 = ks * 32 + lg * 8;
            int g = c0 >> 3;
            float2 st = *(const float2*)&stats[(batch * Gg + g) * 2];
            float4 v0 = *(const float4*)&xr[c0];
            float4 v1 = *(const float4*)&xr[c0 + 4];
            float4 s0 = *(const float4*)&gs[c0];
            float4 s1 = *(const float4*)&gs[c0 + 4];
            float4 b0 = *(const float4*)&gb[c0];
            float4 b1 = *(const float4*)&gb[c0 + 4];
            bf8_t fr;
            fr[0] = (short)f2bf((v0.x - st.x) * st.y * s0.x + b0.x);
            fr[1] = (short)f2bf((v0.y - st.x) * st.y * s0.y + b0.y);
            fr[2] = (short)f2bf((v0.z - st.x) * st.y * s0.z + b0.z);
            fr[3] = (short)f2bf((v0.w - st.x) * st.y * s0.w + b0.w);
            fr[4] = (short)f2bf((v1.x - st.x) * st.y * s1.x + b1.x);
            fr[5] = (short)f2bf((v1.y - st.x) * st.y * s1.y + b1.y);
            fr[6] = (short)f2bf((v1.z - st.x) * st.y * s1.z + b1.z);
            fr[7] = (short)f2bf((v1.w - st.x) * st.y * s1.w + b1.w);
            a[tt][ks] = fr;
        }
    }

#pragma unroll
    for (int which = 0; which < 3; ++which) {
        const ushort* w = wT + which * 65536;
        const float* bias = which == 0 ? bq : which == 1 ? bk : bv;

        f4_t acc[4][4];
#pragma unroll
        for (int tt = 0; tt < 4; ++tt)
#pragma unroll
            for (int i = 0; i < 4; ++i) acc[tt][i] = (f4_t)0.f;

        const ushort* brow = w + (size_t)(nf0 * 16 + lq) * 256 + lg * 8;
#pragma unroll
        for (int nf = 0; nf < 4; ++nf) {
#pragma unroll
            for (int ks = 0; ks < 8; ++ks) {
                bf8_t bfr = *(const bf8_t*)(brow + nf * 16 * 256 + ks * 32);
                acc[0][nf] = __builtin_amdgcn_mfma_f32_16x16x32_bf16(a[0][ks], bfr, acc[0][nf], 0, 0, 0);
                acc[1][nf] = __builtin_amdgcn_mfma_f32_16x16x32_bf16(a[1][ks], bfr, acc[1][nf], 0, 0, 0);
                acc[2][nf] = __builtin_amdgcn_mfma_f32_16x16x32_bf16(a[2][ks], bfr, acc[2][nf], 0, 0, 0);
                acc[3][nf] = __builtin_amdgcn_mfma_f32_16x16x32_bf16(a[3][ks], bfr, acc[3][nf], 0, 0, 0);
            }
        }
#pragma unroll
        for (int tt = 0; tt < 4; ++tt) {
            int m0 = m0b + tt * 16;
            if (which == 2) {
                int bt = m0 >> 12;
                int hw0 = (m0 & 4095) + lg * 4;
#pragma unroll
                for (int nf = 0; nf < 4; ++nf) {
                    int col = (nf0 + nf) * 16 + lq;
                    float bsv = bias[col];
                    ushort4 pk;
                    pk.x = f2bf(acc[tt][nf][0] + bsv);
                    pk.y = f2bf(acc[tt][nf][1] + bsv);
                    pk.z = f2bf(acc[tt][nf][2] + bsv);
                    pk.w = f2bf(acc[tt][nf][3] + bsv);
                    *(ushort4*)&vT[(size_t)bt * (256 * 4096) + (size_t)col * 4096 + hw0] = pk;
                }
            } else {
                ushort* out = which == 0 ? q : k;
                float scale = which == 0 ? QSCALE : 1.0f;
#pragma unroll
                for (int nf = 0; nf < 4; ++nf) {
                    int col = (nf0 + nf) * 16 + lq;
                    float bsv = bias[col];
#pragma unroll
                    for (int r = 0; r < 4; ++r) {
                        int rr = m0 + lg * 4 + r;
                        out[(size_t)rr * 256 + col] = f2bf((acc[tt][nf][r] + bsv) * scale);
                    }
                }
            }
        }
    }
}

// ---------------- flash attention: 4-wave blocks, KVBLK=32, 2 blocks/CU, split-KV x2 ---------
// R20 config; ONLY change: QK accumulates into TWO independent chains (even/odd ks, +16 VGPR)
// merged by one f32x16 add -> dependent-MFMA gap in the QK phase doubles.
__global__ __launch_bounds__(256, 2) void flash_kernel(const ushort* __restrict__ q,
                                                       const ushort* __restrict__ kk,
                                                       const ushort* __restrict__ vT,
                                                       ushort* __restrict__ Opart,
                                                       float* __restrict__ ml) {
    extern __shared__ char smem[];
    const int t = threadIdx.x, lane = t & 63, wvi = t >> 6;   // 4 waves
    const int l31 = lane & 31, hi = lane >> 5;
    const int bid = blockIdx.x;
    const int batch = bid & 7, half = (bid >> 3) & 1, qt = bid >> 4;   // qt 0..31
    const size_t bb = (size_t)batch * HW * Cc;
    const int t0 = half * 64;   // first kv tile (of 128 tiles of 32 kv)

    // Q B-fragments: lane provides q-col = l31, k elems 16ks+8hi..+8  (16 frags = 64 VGPR)
    const int qbase = qt * 128 + wvi * 32;
    bf8_t qf[16];
    {
        const ushort* qrow = q + bb + (size_t)(qbase + l31) * Cc + hi * 8;
#pragma unroll
        for (int ks = 0; ks < 16; ++ks) qf[ks] = *(const bf8_t*)(qrow + ks * 16);
    }

    f32x16 o[8];
#pragma unroll
    for (int i = 0; i < 8; ++i) o[i] = (f32x16)0.f;
    float l_i = 0.f;   // per-lane partial sum of P

    const ushort* ksrc_b = kk + bb;
    const ushort* vsrc_b = vT + (size_t)batch * (256 * 4096);

    auto stage = [&](int kt, int bufsel) {
        const ushort* ks_ = ksrc_b + (size_t)kt * 32 * 256;
        const ushort* vs_ = vsrc_b + kt * 32;
        char* kd = smem + bufsel * 16384;
        char* vd = smem + 32768 + bufsel * 16384;
        // K tile: 32 rows x 512B; LDS slot (kr, c') holds global chunk c = c' ^ (kr&7)
#pragma unroll
        for (int i = 0; i < 4; ++i) {
            int n = i * 256 + t;
            int kr = n >> 5;
            int c = (n & 31) ^ (kr & 7);
            gload16(ks_ + kr * 256 + c * 8, kd + n * 16);
        }
        // Vt tile: 256 rows x 64B; slot (d, c') holds chunk c = c' ^ ((d>>2)&3)
#pragma unroll
        for (int i = 0; i < 4; ++i) {
            int n = i * 256 + t;
            int d = n >> 2;
            int c = (n & 3) ^ ((d >> 2) & 3);
            gload16(vs_ + (size_t)d * HW + c * 8, vd + n * 16);
        }
    };

    stage(t0, 0);
    asm volatile("s_waitcnt vmcnt(0)" ::: "memory");
    __builtin_amdgcn_s_barrier();
    __builtin_amdgcn_sched_barrier(0);

    for (int it = 0; it < 64; ++it) {
        const int cur = it & 1;
        if (it + 1 < 64) stage(t0 + it + 1, cur ^ 1);   // issue next tile's DMAs early

        const char* Kb = smem + cur * 16384;
        const char* Vb = smem + 32768 + cur * 16384;

        // QK^T (swapped, 32x32x16): 2 independent chains (even/odd ks); -8 offset in chain A
        f32x16 sa = (f32x16)(-8.0f);
        f32x16 sb = (f32x16)0.f;
        __builtin_amdgcn_s_setprio(1);
#pragma unroll
        for (int ks = 0; ks < 16; ks += 2) {
            int chA = 2 * ks + hi;
            int swA = (chA ^ (l31 & 7)) * 16;
            int chB = 2 * (ks + 1) + hi;
            int swB = (chB ^ (l31 & 7)) * 16;
            bf8_t kfa = *(const bf8_t*)(Kb + l31 * 512 + swA);
            bf8_t kfb = *(const bf8_t*)(Kb + l31 * 512 + swB);
            sa = __builtin_amdgcn_mfma_f32_32x32x16_bf16(kfa, qf[ks], sa, 0, 0, 0);
            sb = __builtin_amdgcn_mfma_f32_32x32x16_bf16(kfb, qf[ks + 1], sb, 0, 0, 0);
        }
        __builtin_amdgcn_s_setprio(0);
        sa += sb;

        // ---- per-slice: P = exp2(sa), pack to bf16 A-frag, PV MFMAs (VALU || MFMA) ----
#pragma unroll
        for (int s = 0; s < 2; ++s) {
            int b8 = s * 8;
            float p0 = fexp2(sa[b8 + 0]), p1 = fexp2(sa[b8 + 1]);
            float p2 = fexp2(sa[b8 + 2]), p3 = fexp2(sa[b8 + 3]);
            float p4 = fexp2(sa[b8 + 4]), p5 = fexp2(sa[b8 + 5]);
            float p6 = fexp2(sa[b8 + 6]), p7 = fexp2(sa[b8 + 7]);
            l_i += ((p0 + p1) + (p2 + p3)) + ((p4 + p5) + (p6 + p7));
            uint32_t w0 = cvtpk(p0, p1), w1 = cvtpk(p2, p3);
            uint32_t w2 = cvtpk(p4, p5), w3 = cvtpk(p6, p7);
            asm volatile("v_permlane32_swap_b32 %0, %1" : "+v"(w0), "+v"(w2));
            asm volatile("v_permlane32_swap_b32 %0, %1" : "+v"(w1), "+v"(w3));
            union { uint32_t u[4]; bf8_t v; } pa;
            pa.u[0] = w0; pa.u[1] = w1; pa.u[2] = w2; pa.u[3] = w3;

            __builtin_amdgcn_s_setprio(1);
#pragma unroll
            for (int nt = 0; nt < 8; ++nt) {
                int d = nt * 32 + l31;
                int ch = 2 * s + hi;
                bf8_t vf = *(const bf8_t*)(Vb + d * 64 + ((ch ^ ((d >> 2) & 3)) * 16));
                o[nt] = __builtin_amdgcn_mfma_f32_32x32x16_bf16(pa.v, vf, o[nt], 0, 0, 0);
            }
            __builtin_amdgcn_s_setprio(0);
        }

        // single convergence point per tile (4 waves only; other block overlaps)
        if (it + 1 < 64) {
            asm volatile("s_waitcnt vmcnt(0)" ::: "memory");
            __builtin_amdgcn_s_barrier();
            __builtin_amdgcn_sched_barrier(0);
        }
    }

    // epilogue: row l = mine + partner's; store UNNORMALIZED bf16 partial + l per row
    float l_row = l_i + __shfl_xor(l_i, 32);
    ushort* op = Opart + (size_t)bid * (128 * 256) + (size_t)(wvi * 32) * 256;
#pragma unroll
    for (int nt = 0; nt < 8; ++nt) {
#pragma unroll
        for (int r = 0; r < 16; ++r) {
            int qrow = (r & 3) + 8 * (r >> 2) + 4 * hi;
            op[(size_t)qrow * 256 + nt * 32 + l31] = f2bf(o[nt][r]);
        }
    }
    if (lane < 32) {
        ml[(size_t)bid * 128 + wvi * 32 + l31] = l_row;
    }
}

// ---------------- fused combine + proj GEMM + bias + residual (wave = 32 rows x 128 cols) ----
// Both split-KV halves used the same fixed offset, so O = (OA + OB) / (lA + lB).
__global__ __launch_bounds__(256) void projc_gemm(const ushort* __restrict__ Opart,
                                                  const float* __restrict__ ml,
                                                  const ushort* __restrict__ wT,
                                                  const float* __restrict__ bp,
                                                  const float* __restrict__ x,
                                                  float* __restrict__ outp) {
    int lane = threadIdx.x & 63, wvi = threadIdx.x >> 6;
    int lq = lane & 15, lg = lane >> 4;
    int rowhalf = wvi >> 1, nf0 = (wvi & 1) * 8;
    int m0b = blockIdx.x * 64 + rowhalf * 32;

    bf8_t a[2][8];
#pragma unroll
    for (int tt = 0; tt < 2; ++tt) {
        int row = m0b + tt * 16 + lq;
        int batch = row >> 12, rr = row & 4095;
        int qt = rr >> 7, rit = rr & 127;
        int blkA = batch + 16 * qt, blkB = blkA + 8;
        float la = ml[(size_t)blkA * 128 + rit];
        float lb = ml[(size_t)blkB * 128 + rit];
        float inv = 1.0f / (la + lb);
        const ushort* Arow = Opart + (size_t)blkA * 32768 + (size_t)rit * 256 + lg * 8;
        const ushort* Brow = Opart + (size_t)blkB * 32768 + (size_t)rit * 256 + lg * 8;
#pragma unroll
        for (int ks = 0; ks < 8; ++ks) {
            bf8_t fa = *(const bf8_t*)(Arow + ks * 32);
            bf8_t fb = *(const bf8_t*)(Brow + ks * 32);
            bf8_t mg;
#pragma unroll
            for (int j = 0; j < 8; ++j)
                mg[j] = (short)f2bf((bf2f((ushort)fa[j]) + bf2f((ushort)fb[j])) * inv);
            a[tt][ks] = mg;
        }
    }

    f4_t acc[2][8];
#pragma unroll
    for (int tt = 0; tt < 2; ++tt)
#pragma unroll
        for (int i = 0; i < 8; ++i) acc[tt][i] = (f4_t)0.f;

    const ushort* brow = wT + (size_t)(nf0 * 16 + lq) * 256 + lg * 8;
#pragma unroll
    for (int nf = 0; nf < 8; ++nf) {
#pragma unroll
        for (int ks = 0; ks < 8; ++ks) {
            bf8_t bfr = *(const bf8_t*)(brow + nf * 16 * 256 + ks * 32);
            acc[0][nf] = __builtin_amdgcn_mfma_f32_16x16x32_bf16(a[0][ks], bfr, acc[0][nf], 0, 0, 0);
            acc[1][nf] = __builtin_amdgcn_mfma_f32_16x16x32_bf16(a[1][ks], bfr, acc[1][nf], 0, 0, 0);
        }
    }
#pragma unroll
    for (int tt = 0; tt < 2; ++tt) {
#pragma unroll
        for (int nf = 0; nf < 8; ++nf) {
            int col = (nf0 + nf) * 16 + lq;
            float bsv = bp[col];
#pragma unroll
            for (int r = 0; r < 4; ++r) {
                size_t idx = (size_t)(m0b + tt * 16 + lg * 4 + r) * 256 + col;
                outp[idx] = x[idx] + acc[tt][nf][r] + bsv;
            }
        }
    }
}

extern "C" void kernel_launch(void* const* d_in, const int* in_sizes, int n_in,
                              void* d_out, int out_size, void* d_ws, size_t ws_size,
                              hipStream_t stream) {
    const float* x  = (const float*)d_in[0];
    const float* gs = (const float*)d_in[1];
    const float* gb = (const float*)d_in[2];
    const float* wq = (const float*)d_in[3];
    const float* bq = (const float*)d_in[4];
    const float* wk = (const float*)d_in[5];
    const float* bk = (const float*)d_in[6];
    const float* wv = (const float*)d_in[7];
    const float* bv = (const float*)d_in[8];
    const float* wp = (const float*)d_in[9];
    const float* bp = (const float*)d_in[10];
    float* out = (float*)d_out;

    char* ws = (char*)d_ws;
    ushort* wT    = (ushort*)ws;                         // 512 KB
    float*  psum  = (float*)(ws + 512 * 1024);           // 64 KB
    float*  psumsq= (float*)(ws + 576 * 1024);           // 64 KB
    float*  stats = (float*)(ws + 640 * 1024);           // 2 KB
    ushort* qb    = (ushort*)(ws + (size_t)17 * (1 << 20));
    ushort* kb    = (ushort*)(ws + (size_t)33 * (1 << 20));
    ushort* vTb   = (ushort*)(ws + (size_t)49 * (1 << 20));   // V transposed [b][d][hw]
    ushort* Opart = (ushort*)(ws + (size_t)65 * (1 << 20));   // 32 MB: 512 x 128 x 256 bf16
    float*  mlb   = (float*)(ws + (size_t)97 * (1 << 20));    // 256 KB: 512 x 128 float

    prep_kernel<<<768, 256, 0, stream>>>(x, psum, psumsq, wq, wk, wv, wp, wT);
    gn_stats<<<1, 256, 0, stream>>>(psum, psumsq, stats);
    qkv_gn<<<512, 256, 0, stream>>>(x, stats, gs, gb, wT, bq, bk, bv, qb, kb, vTb);

    hipFuncSetAttribute(reinterpret_cast<const void*>(flash_kernel),
                        hipFuncAttributeMaxDynamicSharedMemorySize, 65536);
    flash_kernel<<<512, 256, 65536, stream>>>(qb, kb, vTb, Opart, mlb);

    projc_gemm<<<512, 256, 0, stream>>>(Opart, mlb, wT + 3 * 65536, bp, x, out);
}

// Round 22
// 247.972 us; speedup vs baseline: 1.1319x; 1.1319x over previous
//
#include <hip/hip_runtime.h>
#include <hip/hip_bf16.h>
#include <stdint.h>

// ---- problem constants ----
static constexpr int HW = 4096;     // 64*64
static constexpr int Cc = 256;
static constexpr int Gg = 32;
static constexpr float EPSV = 1e-6f;
static constexpr float QSCALE = 0.0625f * 1.44269504f;   // c^-0.5 * log2(e): softmax in exp2 domain

typedef __attribute__((ext_vector_type(8))) short bf8_t;     // 8 bf16 (4 VGPR)
typedef __attribute__((ext_vector_type(4))) float f4_t;      // 16x16 mfma acc
typedef __attribute__((ext_vector_type(16))) float f32x16;   // 32x32 mfma acc

__device__ __forceinline__ ushort f2bf(float x) {
    union { float f; uint32_t u; } v; v.f = x;
    uint32_t r = v.u + 0x7FFFu + ((v.u >> 16) & 1u);
    return (ushort)(r >> 16);
}
__device__ __forceinline__ float bf2f(ushort u) {
    union { uint32_t u; float f; } v; v.u = ((uint32_t)u) << 16;
    return v.f;
}
__device__ __forceinline__ uint32_t cvtpk(float lo, float hi_) {
    uint32_t r;
    asm volatile("v_cvt_pk_bf16_f32 %0, %1, %2" : "=v"(r) : "v"(lo), "v"(hi_));
    return r;
}
__device__ __forceinline__ float fexp2(float x) {   // raw v_exp_f32
    float r;
    asm("v_exp_f32 %0, %1" : "=v"(r) : "v"(x));
    return r;
}

// async global->LDS DMA, 16B per lane; lds dest is wave-uniform base (+lane*16 by HW)
__device__ __forceinline__ void gload16(const void* g, void* l) {
    __builtin_amdgcn_global_load_lds((const __attribute__((address_space(1))) void*)g,
                                     (__attribute__((address_space(3))) void*)l, 16, 0, 0);
}

// ---------------- prep: GN partial sums (blocks 0..511) + weight transpose (blocks 512..767) --
// wT[which][d][c] = bf16(w[c][d])
__global__ void prep_kernel(const float* __restrict__ x, float* __restrict__ psum,
                            float* __restrict__ psumsq,
                            const float* __restrict__ wq, const float* __restrict__ wk,
                            const float* __restrict__ wv, const float* __restrict__ wp,
                            ushort* __restrict__ wT) {
    int bx = blockIdx.x;
    if (bx < 512) {
        int slice = bx & 63;
        int b = bx >> 6;
        int c = threadIdx.x;
        const float* xp = x + ((size_t)b * HW + (size_t)slice * 64) * Cc + c;
        float s = 0.f, sq = 0.f;
        for (int p = 0; p < 64; ++p) { float v = xp[(size_t)p * Cc]; s += v; sq += v * v; }
        for (int m = 1; m < 8; m <<= 1) { s += __shfl_xor(s, m); sq += __shfl_xor(sq, m); }
        if ((c & 7) == 0) {
            int g = c >> 3;
            psum[(b * Gg + g) * 64 + slice] = s;
            psumsq[(b * Gg + g) * 64 + slice] = sq;
        }
    } else {
        int base = (bx - 512) * 1024 + threadIdx.x * 4;   // 4 consecutive c, same d
        int which = base >> 16;
        const float* w = which == 0 ? wq : which == 1 ? wk : which == 2 ? wv : wp;
        int rem = base & 65535;
        int d = rem >> 8, c = rem & 255;
        ushort4 o;
        o.x = f2bf(w[(c + 0) * 256 + d]);
        o.y = f2bf(w[(c + 1) * 256 + d]);
        o.z = f2bf(w[(c + 2) * 256 + d]);
        o.w = f2bf(w[(c + 3) * 256 + d]);
        *(ushort4*)&wT[which * 65536 + d * 256 + c] = o;
    }
}

__global__ void gn_stats(const float* __restrict__ psum, const float* __restrict__ psumsq,
                         float* __restrict__ stats) {
    int t = threadIdx.x;  // 256 = b*32+g
    float s = 0.f, sq = 0.f;
    for (int i = 0; i < 64; ++i) { s += psum[t * 64 + i]; sq += psumsq[t * 64 + i]; }
    float mean = s * (1.0f / 32768.0f);
    float var = sq * (1.0f / 32768.0f) - mean * mean;
    stats[t * 2] = mean;
    stats[t * 2 + 1] = rsqrtf(var + EPSV);
}

// ---------------- fused GN-normalize + QKV GEMM (wave = 64 rows x 64 cols) ----------------
__global__ __launch_bounds__(256) void qkv_gn(const float* __restrict__ x, const float* __restrict__ stats,
                                              const float* __restrict__ gs, const float* __restrict__ gb,
                                              const ushort* __restrict__ wT,
                                              const float* __restrict__ bq, const float* __restrict__ bk,
                                              const float* __restrict__ bv,
                                              ushort* __restrict__ q, ushort* __restrict__ k,
                                              ushort* __restrict__ vT) {
    int lane = threadIdx.x & 63, wvi = threadIdx.x >> 6;
    int lq = lane & 15, lg = lane >> 4;
    int nf0 = wvi * 4;                  // wave's 4 col-tiles (64 cols)
    int m0b = blockIdx.x * 64;          // block's 64 rows (shared by all 4 waves)

    bf8_t a[4][8];
#pragma unroll
    for (int tt = 0; tt < 4; ++tt) {
        int row = m0b + tt * 16 + lq;
        int batch = row >> 12;
        const float* xr = x + (size_t)row * 256;
#pragma unroll
        for (int ks = 0; ks < 8; ++ks) {
            int c0 = ks * 32 + lg * 8;
            int g = c0 >> 3;
            float2 st = *(const float2*)&stats[(batch * Gg + g) * 2];
            float4 v0 = *(const float4*)&xr[c0];
            float4 v1 = *(const float4*)&xr[c0 + 4];
            float4 s0 = *(const float4*)&gs[c0];
            float4 s1 = *(const float4*)&gs[c0 + 4];
            float4 b0 = *(const float4*)&gb[c0];
            float4 b1 = *(const float4*)&gb[c0 + 4];
            bf8_t fr;
            fr[0] = (short)f2bf((v0.x - st.x) * st.y * s0.x + b0.x);
            fr[1] = (short)f2bf((v0.y - st.x) * st.y * s0.y + b0.y);
            fr[2] = (short)f2bf((v0.z - st.x) * st.y * s0.z + b0.z);
            fr[3] = (short)f2bf((v0.w - st.x) * st.y * s0.w + b0.w);
            fr[4] = (short)f2bf((v1.x - st.x) * st.y * s1.x + b1.x);
            fr[5] = (short)f2bf((v1.y - st.x) * st.y * s1.y + b1.y);
            fr[6] = (short)f2bf((v1.z - st.x) * st.y * s1.z + b1.z);
            fr[7] = (short)f2bf((v1.w - st.x) * st.y * s1.w + b1.w);
            a[tt][ks] = fr;
        }
    }

#pragma unroll
    for (int which = 0; which < 3; ++which) {
        const ushort* w = wT + which * 65536;
        const float* bias = which == 0 ? bq : which == 1 ? bk : bv;

        f4_t acc[4][4];
#pragma unroll
        for (int tt = 0; tt < 4; ++tt)
#pragma unroll
            for (int i = 0; i < 4; ++i) acc[tt][i] = (f4_t)0.f;

        const ushort* brow = w + (size_t)(nf0 * 16 + lq) * 256 + lg * 8;
#pragma unroll
        for (int nf = 0; nf < 4; ++nf) {
#pragma unroll
            for (int ks = 0; ks < 8; ++ks) {
                bf8_t bfr = *(const bf8_t*)(brow + nf * 16 * 256 + ks * 32);
                acc[0][nf] = __builtin_amdgcn_mfma_f32_16x16x32_bf16(a[0][ks], bfr, acc[0][nf], 0, 0, 0);
                acc[1][nf] = __builtin_amdgcn_mfma_f32_16x16x32_bf16(a[1][ks], bfr, acc[1][nf], 0, 0, 0);
                acc[2][nf] = __builtin_amdgcn_mfma_f32_16x16x32_bf16(a[2][ks], bfr, acc[2][nf], 0, 0, 0);
                acc[3][nf] = __builtin_amdgcn_mfma_f32_16x16x32_bf16(a[3][ks], bfr, acc[3][nf], 0, 0, 0);
            }
        }
#pragma unroll
        for (int tt = 0; tt < 4; ++tt) {
            int m0 = m0b + tt * 16;
            if (which == 2) {
                int bt = m0 >> 12;
                int hw0 = (m0 & 4095) + lg * 4;
#pragma unroll
                for (int nf = 0; nf < 4; ++nf) {
                    int col = (nf0 + nf) * 16 + lq;
                    float bsv = bias[col];
                    ushort4 pk;
                    pk.x = f2bf(acc[tt][nf][0] + bsv);
                    pk.y = f2bf(acc[tt][nf][1] + bsv);
                    pk.z = f2bf(acc[tt][nf][2] + bsv);
                    pk.w = f2bf(acc[tt][nf][3] + bsv);
                    *(ushort4*)&vT[(size_t)bt * (256 * 4096) + (size_t)col * 4096 + hw0] = pk;
                }
            } else {
                ushort* out = which == 0 ? q : k;
                float scale = which == 0 ? QSCALE : 1.0f;
#pragma unroll
                for (int nf = 0; nf < 4; ++nf) {
                    int col = (nf0 + nf) * 16 + lq;
                    float bsv = bias[col];
#pragma unroll
                    for (int r = 0; r < 4; ++r) {
                        int rr = m0 + lg * 4 + r;
                        out[(size_t)rr * 256 + col] = f2bf((acc[tt][nf][r] + bsv) * scale);
                    }
                }
            }
        }
    }
}

// ---------------- flash attention: 4-wave blocks, KVBLK=32, 2 blocks/CU, split-KV x2 ---------
// R20 config VERBATIM (best measured: 162us): gload_lds XOR staging (K: c'^(kr&7),
// V: c'^((d>>2)&3) 4-way), single barrier/tile, fixed-offset softmax P=exp2(S-8) with a
// SINGLE QK accumulator chain (chain-splitting regressed twice: R16, R21).
__global__ __launch_bounds__(256, 2) void flash_kernel(const ushort* __restrict__ q,
                                                       const ushort* __restrict__ kk,
                                                       const ushort* __restrict__ vT,
                                                       ushort* __restrict__ Opart,
                                                       float* __restrict__ ml) {
    extern __shared__ char smem[];
    const int t = threadIdx.x, lane = t & 63, wvi = t >> 6;   // 4 waves
    const int l31 = lane & 31, hi = lane >> 5;
    const int bid = blockIdx.x;
    const int batch = bid & 7, half = (bid >> 3) & 1, qt = bid >> 4;   // qt 0..31
    const size_t bb = (size_t)batch * HW * Cc;
    const int t0 = half * 64;   // first kv tile (of 128 tiles of 32 kv)

    // Q B-fragments: lane provides q-col = l31, k elems 16ks+8hi..+8  (16 frags = 64 VGPR)
    const int qbase = qt * 128 + wvi * 32;
    bf8_t qf[16];
    {
        const ushort* qrow = q + bb + (size_t)(qbase + l31) * Cc + hi * 8;
#pragma unroll
        for (int ks = 0; ks < 16; ++ks) qf[ks] = *(const bf8_t*)(qrow + ks * 16);
    }

    f32x16 o[8];
#pragma unroll
    for (int i = 0; i < 8; ++i) o[i] = (f32x16)0.f;
    float l_i = 0.f;   // per-lane partial sum of P

    const ushort* ksrc_b = kk + bb;
    const ushort* vsrc_b = vT + (size_t)batch * (256 * 4096);

    auto stage = [&](int kt, int bufsel) {
        const ushort* ks_ = ksrc_b + (size_t)kt * 32 * 256;
        const ushort* vs_ = vsrc_b + kt * 32;
        char* kd = smem + bufsel * 16384;
        char* vd = smem + 32768 + bufsel * 16384;
        // K tile: 32 rows x 512B; LDS slot (kr, c') holds global chunk c = c' ^ (kr&7)
#pragma unroll
        for (int i = 0; i < 4; ++i) {
            int n = i * 256 + t;
            int kr = n >> 5;
            int c = (n & 31) ^ (kr & 7);
            gload16(ks_ + kr * 256 + c * 8, kd + n * 16);
        }
        // Vt tile: 256 rows x 64B; slot (d, c') holds chunk c = c' ^ ((d>>2)&3)
#pragma unroll
        for (int i = 0; i < 4; ++i) {
            int n = i * 256 + t;
            int d = n >> 2;
            int c = (n & 3) ^ ((d >> 2) & 3);
            gload16(vs_ + (size_t)d * HW + c * 8, vd + n * 16);
        }
    };

    stage(t0, 0);
    asm volatile("s_waitcnt vmcnt(0)" ::: "memory");
    __builtin_amdgcn_s_barrier();
    __builtin_amdgcn_sched_barrier(0);

    for (int it = 0; it < 64; ++it) {
        const int cur = it & 1;
        if (it + 1 < 64) stage(t0 + it + 1, cur ^ 1);   // issue next tile's DMAs early

        const char* Kb = smem + cur * 16384;
        const char* Vb = smem + 32768 + cur * 16384;

        // QK^T (swapped, 32x32x16), acc init -8 bakes in the fixed softmax offset
        f32x16 sa = (f32x16)(-8.0f);
        __builtin_amdgcn_s_setprio(1);
#pragma unroll
        for (int ks = 0; ks < 16; ++ks) {
            int chunk = 2 * ks + hi;
            int sw = (chunk ^ (l31 & 7)) * 16;
            bf8_t kf = *(const bf8_t*)(Kb + l31 * 512 + sw);
            sa = __builtin_amdgcn_mfma_f32_32x32x16_bf16(kf, qf[ks], sa, 0, 0, 0);
        }
        __builtin_amdgcn_s_setprio(0);

        // ---- per-slice: P = exp2(sa), pack to bf16 A-frag, PV MFMAs (VALU || MFMA) ----
#pragma unroll
        for (int s = 0; s < 2; ++s) {
            int b8 = s * 8;
            float p0 = fexp2(sa[b8 + 0]), p1 = fexp2(sa[b8 + 1]);
            float p2 = fexp2(sa[b8 + 2]), p3 = fexp2(sa[b8 + 3]);
            float p4 = fexp2(sa[b8 + 4]), p5 = fexp2(sa[b8 + 5]);
            float p6 = fexp2(sa[b8 + 6]), p7 = fexp2(sa[b8 + 7]);
            l_i += ((p0 + p1) + (p2 + p3)) + ((p4 + p5) + (p6 + p7));
            uint32_t w0 = cvtpk(p0, p1), w1 = cvtpk(p2, p3);
            uint32_t w2 = cvtpk(p4, p5), w3 = cvtpk(p6, p7);
            asm volatile("v_permlane32_swap_b32 %0, %1" : "+v"(w0), "+v"(w2));
            asm volatile("v_permlane32_swap_b32 %0, %1" : "+v"(w1), "+v"(w3));
            union { uint32_t u[4]; bf8_t v; } pa;
            pa.u[0] = w0; pa.u[1] = w1; pa.u[2] = w2; pa.u[3] = w3;

            __builtin_amdgcn_s_setprio(1);
#pragma unroll
            for (int nt = 0; nt < 8; ++nt) {
                int d = nt * 32 + l31;
                int ch = 2 * s + hi;
                bf8_t vf = *(const bf8_t*)(Vb + d * 64 + ((ch ^ ((d >> 2) & 3)) * 16));
                o[nt] = __builtin_amdgcn_mfma_f32_32x32x16_bf16(pa.v, vf, o[nt], 0, 0, 0);
            }
            __builtin_amdgcn_s_setprio(0);
        }

        // single convergence point per tile (4 waves only; other block overlaps)
        if (it + 1 < 64) {
            asm volatile("s_waitcnt vmcnt(0)" ::: "memory");
            __builtin_amdgcn_s_barrier();
            __builtin_amdgcn_sched_barrier(0);
        }
    }

    // epilogue: row l = mine + partner's; store UNNORMALIZED bf16 partial + l per row
    float l_row = l_i + __shfl_xor(l_i, 32);
    ushort* op = Opart + (size_t)bid * (128 * 256) + (size_t)(wvi * 32) * 256;
#pragma unroll
    for (int nt = 0; nt < 8; ++nt) {
#pragma unroll
        for (int r = 0; r < 16; ++r) {
            int qrow = (r & 3) + 8 * (r >> 2) + 4 * hi;
            op[(size_t)qrow * 256 + nt * 32 + l31] = f2bf(o[nt][r]);
        }
    }
    if (lane < 32) {
        ml[(size_t)bid * 128 + wvi * 32 + l31] = l_row;
    }
}

// ---------------- fused combine + proj GEMM + bias + residual (wave = 32 rows x 128 cols) ----
// Both split-KV halves used the same fixed offset, so O = (OA + OB) / (lA + lB).
__global__ __launch_bounds__(256) void projc_gemm(const ushort* __restrict__ Opart,
                                                  const float* __restrict__ ml,
                                                  const ushort* __restrict__ wT,
                                                  const float* __restrict__ bp,
                                                  const float* __restrict__ x,
                                                  float* __restrict__ outp) {
    int lane = threadIdx.x & 63, wvi = threadIdx.x >> 6;
    int lq = lane & 15, lg = lane >> 4;
    int rowhalf = wvi >> 1, nf0 = (wvi & 1) * 8;
    int m0b = blockIdx.x * 64 + rowhalf * 32;

    bf8_t a[2][8];
#pragma unroll
    for (int tt = 0; tt < 2; ++tt) {
        int row = m0b + tt * 16 + lq;
        int batch = row >> 12, rr = row & 4095;
        int qt = rr >> 7, rit = rr & 127;
        int blkA = batch + 16 * qt, blkB = blkA + 8;
        float la = ml[(size_t)blkA * 128 + rit];
        float lb = ml[(size_t)blkB * 128 + rit];
        float inv = 1.0f / (la + lb);
        const ushort* Arow = Opart + (size_t)blkA * 32768 + (size_t)rit * 256 + lg * 8;
        const ushort* Brow = Opart + (size_t)blkB * 32768 + (size_t)rit * 256 + lg * 8;
#pragma unroll
        for (int ks = 0; ks < 8; ++ks) {
            bf8_t fa = *(const bf8_t*)(Arow + ks * 32);
            bf8_t fb = *(const bf8_t*)(Brow + ks * 32);
            bf8_t mg;
#pragma unroll
            for (int j = 0; j < 8; ++j)
                mg[j] = (short)f2bf((bf2f((ushort)fa[j]) + bf2f((ushort)fb[j])) * inv);
            a[tt][ks] = mg;
        }
    }

    f4_t acc[2][8];
#pragma unroll
    for (int tt = 0; tt < 2; ++tt)
#pragma unroll
        for (int i = 0; i < 8; ++i) acc[tt][i] = (f4_t)0.f;

    const ushort* brow = wT + (size_t)(nf0 * 16 + lq) * 256 + lg * 8;
#pragma unroll
    for (int nf = 0; nf < 8; ++nf) {
#pragma unroll
        for (int ks = 0; ks < 8; ++ks) {
            bf8_t bfr = *(const bf8_t*)(brow + nf * 16 * 256 + ks * 32);
            acc[0][nf] = __builtin_amdgcn_mfma_f32_16x16x32_bf16(a[0][ks], bfr, acc[0][nf], 0, 0, 0);
            acc[1][nf] = __builtin_amdgcn_mfma_f32_16x16x32_bf16(a[1][ks], bfr, acc[1][nf], 0, 0, 0);
        }
    }
#pragma unroll
    for (int tt = 0; tt < 2; ++tt) {
#pragma unroll
        for (int nf = 0; nf < 8; ++nf) {
            int col = (nf0 + nf) * 16 + lq;
            float bsv = bp[col];
#pragma unroll
            for (int r = 0; r < 4; ++r) {
                size_t idx = (size_t)(m0b + tt * 16 + lg * 4 + r) * 256 + col;
                outp[idx] = x[idx] + acc[tt][nf][r] + bsv;
            }
        }
    }
}

extern "C" void kernel_launch(void* const* d_in, const int* in_sizes, int n_in,
                              void* d_out, int out_size, void* d_ws, size_t ws_size,
                              hipStream_t stream) {
    const float* x  = (const float*)d_in[0];
    const float* gs = (const float*)d_in[1];
    const float* gb = (const float*)d_in[2];
    const float* wq = (const float*)d_in[3];
    const float* bq = (const float*)d_in[4];
    const float* wk = (const float*)d_in[5];
    const float* bk = (const float*)d_in[6];
    const float* wv = (const float*)d_in[7];
    const float* bv = (const float*)d_in[8];
    const float* wp = (const float*)d_in[9];
    const float* bp = (const float*)d_in[10];
    float* out = (float*)d_out;

    char* ws = (char*)d_ws;
    ushort* wT    = (ushort*)ws;                         // 512 KB
    float*  psum  = (float*)(ws + 512 * 1024);           // 64 KB
    float*  psumsq= (float*)(ws + 576 * 1024);           // 64 KB
    float*  stats = (float*)(ws + 640 * 1024);           // 2 KB
    ushort* qb    = (ushort*)(ws + (size_t)17 * (1 << 20));
    ushort* kb    = (ushort*)(ws + (size_t)33 * (1 << 20));
    ushort* vTb   = (ushort*)(ws + (size_t)49 * (1 << 20));   // V transposed [b][d][hw]
    ushort* Opart = (ushort*)(ws + (size_t)65 * (1 << 20));   // 32 MB: 512 x 128 x 256 bf16
    float*  mlb   = (float*)(ws + (size_t)97 * (1 << 20));    // 256 KB: 512 x 128 float

    prep_kernel<<<768, 256, 0, stream>>>(x, psum, psumsq, wq, wk, wv, wp, wT);
    gn_stats<<<1, 256, 0, stream>>>(psum, psumsq, stats);
    qkv_gn<<<512, 256, 0, stream>>>(x, stats, gs, gb, wT, bq, bk, bv, qb, kb, vTb);

    hipFuncSetAttribute(reinterpret_cast<const void*>(flash_kernel),
                        hipFuncAttributeMaxDynamicSharedMemorySize, 65536);
    flash_kernel<<<512, 256, 65536, stream>>>(qb, kb, vTb, Opart, mlb);

    projc_gemm<<<512, 256, 0, stream>>>(Opart, mlb, wT + 3 * 65536, bp, x, out);
}

// Round 23
// 240.682 us; speedup vs baseline: 1.1662x; 1.0303x over previous
//
#include <hip/hip_runtime.h>
#include <hip/hip_bf16.h>
#include <stdint.h>

// ---- problem constants ----
static constexpr int HW = 4096;     // 64*64
static constexpr int Cc = 256;
static constexpr int Gg = 32;
static constexpr float EPSV = 1e-6f;
static constexpr float QSCALE = 0.0625f * 1.44269504f;   // c^-0.5 * log2(e): softmax in exp2 domain

typedef __attribute__((ext_vector_type(8))) short bf8_t;     // 8 bf16 (4 VGPR)
typedef __attribute__((ext_vector_type(4))) float f4_t;      // 16x16 mfma acc
typedef __attribute__((ext_vector_type(16))) float f32x16;   // 32x32 mfma acc

__device__ __forceinline__ ushort f2bf(float x) {
    union { float f; uint32_t u; } v; v.f = x;
    uint32_t r = v.u + 0x7FFFu + ((v.u >> 16) & 1u);
    return (ushort)(r >> 16);
}
__device__ __forceinline__ float bf2f(ushort u) {
    union { uint32_t u; float f; } v; v.u = ((uint32_t)u) << 16;
    return v.f;
}
__device__ __forceinline__ uint32_t cvtpk(float lo, float hi_) {
    uint32_t r;
    asm volatile("v_cvt_pk_bf16_f32 %0, %1, %2" : "=v"(r) : "v"(lo), "v"(hi_));
    return r;
}
__device__ __forceinline__ float fexp2(float x) {   // raw v_exp_f32
    float r;
    asm("v_exp_f32 %0, %1" : "=v"(r) : "v"(x));
    return r;
}

// async global->LDS DMA, 16B per lane; lds dest is wave-uniform base (+lane*16 by HW)
__device__ __forceinline__ void gload16(const void* g, void* l) {
    __builtin_amdgcn_global_load_lds((const __attribute__((address_space(1))) void*)g,
                                     (__attribute__((address_space(3))) void*)l, 16, 0, 0);
}

// ---------------- prep: GN partial sums (blocks 0..511) + weight transpose (blocks 512..767) --
// wT[which][d][c] = bf16(w[c][d])
__global__ void prep_kernel(const float* __restrict__ x, float* __restrict__ psum,
                            float* __restrict__ psumsq,
                            const float* __restrict__ wq, const float* __restrict__ wk,
                            const float* __restrict__ wv, const float* __restrict__ wp,
                            ushort* __restrict__ wT) {
    int bx = blockIdx.x;
    if (bx < 512) {
        int slice = bx & 63;
        int b = bx >> 6;
        int c = threadIdx.x;
        const float* xp = x + ((size_t)b * HW + (size_t)slice * 64) * Cc + c;
        float s = 0.f, sq = 0.f;
        for (int p = 0; p < 64; ++p) { float v = xp[(size_t)p * Cc]; s += v; sq += v * v; }
        for (int m = 1; m < 8; m <<= 1) { s += __shfl_xor(s, m); sq += __shfl_xor(sq, m); }
        if ((c & 7) == 0) {
            int g = c >> 3;
            psum[(b * Gg + g) * 64 + slice] = s;
            psumsq[(b * Gg + g) * 64 + slice] = sq;
        }
    } else {
        int base = (bx - 512) * 1024 + threadIdx.x * 4;   // 4 consecutive c, same d
        int which = base >> 16;
        const float* w = which == 0 ? wq : which == 1 ? wk : which == 2 ? wv : wp;
        int rem = base & 65535;
        int d = rem >> 8, c = rem & 255;
        ushort4 o;
        o.x = f2bf(w[(c + 0) * 256 + d]);
        o.y = f2bf(w[(c + 1) * 256 + d]);
        o.z = f2bf(w[(c + 2) * 256 + d]);
        o.w = f2bf(w[(c + 3) * 256 + d]);
        *(ushort4*)&wT[which * 65536 + d * 256 + c] = o;
    }
}

__global__ void gn_stats(const float* __restrict__ psum, const float* __restrict__ psumsq,
                         float* __restrict__ stats) {
    int t = threadIdx.x;  // 256 = b*32+g
    float s = 0.f, sq = 0.f;
    for (int i = 0; i < 64; ++i) { s += psum[t * 64 + i]; sq += psumsq[t * 64 + i]; }
    float mean = s * (1.0f / 32768.0f);
    float var = sq * (1.0f / 32768.0f) - mean * mean;
    stats[t * 2] = mean;
    stats[t * 2 + 1] = rsqrtf(var + EPSV);
}

// ---------------- fused GN-normalize + QKV GEMM (LDS-staged normalize, wave = 64r x 64c) ----
// Phase 1: block cooperatively normalizes its 64 rows ONCE into padded LDS (pitch 528B,
// bank-clean for both write and A-frag read). Phase 2: waves load a[4][8] from LDS and run
// the 3 GEMMs (nf-quarter split, each wave streams 1/4 of wT). Removes the 4x-redundant
// x reads + normalize VALU of the previous all-register version.
__global__ __launch_bounds__(256) void qkv_gn(const float* __restrict__ x, const float* __restrict__ stats,
                                              const float* __restrict__ gs, const float* __restrict__ gb,
                                              const ushort* __restrict__ wT,
                                              const float* __restrict__ bq, const float* __restrict__ bk,
                                              const float* __restrict__ bv,
                                              ushort* __restrict__ q, ushort* __restrict__ k,
                                              ushort* __restrict__ vT) {
    __shared__ __align__(16) char sm[64 * 528];
    int t = threadIdx.x;
    int lane = t & 63, wvi = t >> 6;
    int lq = lane & 15, lg = lane >> 4;
    int nf0 = wvi * 4;                  // wave's 4 col-tiles (64 cols)
    int m0b = blockIdx.x * 64;          // block's 64 rows

    // ---- phase 1: normalize 64 rows once into LDS ----
    {
        int row = t >> 2, q4 = t & 3;            // 64 els: cols q4*64 .. +63
        int xrow = m0b + row;
        int batch = xrow >> 12;
        const float* xr = x + (size_t)xrow * 256;
        char* lrow = sm + row * 528;
#pragma unroll
        for (int i = 0; i < 8; ++i) {
            int c0 = q4 * 64 + i * 8;
            int g = c0 >> 3;
            float2 st = *(const float2*)&stats[(batch * Gg + g) * 2];
            float4 v0 = *(const float4*)&xr[c0];
            float4 v1 = *(const float4*)&xr[c0 + 4];
            float4 s0 = *(const float4*)&gs[c0];
            float4 s1 = *(const float4*)&gs[c0 + 4];
            float4 b0 = *(const float4*)&gb[c0];
            float4 b1 = *(const float4*)&gb[c0 + 4];
            ushort8_t_dummy:;
            union { ushort u[8]; uint4 v; } pk;
            pk.u[0] = f2bf((v0.x - st.x) * st.y * s0.x + b0.x);
            pk.u[1] = f2bf((v0.y - st.x) * st.y * s0.y + b0.y);
            pk.u[2] = f2bf((v0.z - st.x) * st.y * s0.z + b0.z);
            pk.u[3] = f2bf((v0.w - st.x) * st.y * s0.w + b0.w);
            pk.u[4] = f2bf((v1.x - st.x) * st.y * s1.x + b1.x);
            pk.u[5] = f2bf((v1.y - st.x) * st.y * s1.y + b1.y);
            pk.u[6] = f2bf((v1.z - st.x) * st.y * s1.z + b1.z);
            pk.u[7] = f2bf((v1.w - st.x) * st.y * s1.w + b1.w);
            *(uint4*)(lrow + c0 * 2) = pk.v;
        }
    }
    __syncthreads();

    // ---- phase 2: load A-fragments from LDS (once), then 3 GEMMs ----
    bf8_t a[4][8];
#pragma unroll
    for (int tt = 0; tt < 4; ++tt)
#pragma unroll
        for (int ks = 0; ks < 8; ++ks)
            a[tt][ks] = *(const bf8_t*)(sm + (tt * 16 + lq) * 528 + (ks * 32 + lg * 8) * 2);

#pragma unroll
    for (int which = 0; which < 3; ++which) {
        const ushort* w = wT + which * 65536;
        const float* bias = which == 0 ? bq : which == 1 ? bk : bv;

        f4_t acc[4][4];
#pragma unroll
        for (int tt = 0; tt < 4; ++tt)
#pragma unroll
            for (int i = 0; i < 4; ++i) acc[tt][i] = (f4_t)0.f;

        const ushort* brow = w + (size_t)(nf0 * 16 + lq) * 256 + lg * 8;
#pragma unroll
        for (int nf = 0; nf < 4; ++nf) {
#pragma unroll
            for (int ks = 0; ks < 8; ++ks) {
                bf8_t bfr = *(const bf8_t*)(brow + nf * 16 * 256 + ks * 32);
                acc[0][nf] = __builtin_amdgcn_mfma_f32_16x16x32_bf16(a[0][ks], bfr, acc[0][nf], 0, 0, 0);
                acc[1][nf] = __builtin_amdgcn_mfma_f32_16x16x32_bf16(a[1][ks], bfr, acc[1][nf], 0, 0, 0);
                acc[2][nf] = __builtin_amdgcn_mfma_f32_16x16x32_bf16(a[2][ks], bfr, acc[2][nf], 0, 0, 0);
                acc[3][nf] = __builtin_amdgcn_mfma_f32_16x16x32_bf16(a[3][ks], bfr, acc[3][nf], 0, 0, 0);
            }
        }
#pragma unroll
        for (int tt = 0; tt < 4; ++tt) {
            int m0 = m0b + tt * 16;
            if (which == 2) {
                int bt = m0 >> 12;
                int hw0 = (m0 & 4095) + lg * 4;
#pragma unroll
                for (int nf = 0; nf < 4; ++nf) {
                    int col = (nf0 + nf) * 16 + lq;
                    float bsv = bias[col];
                    ushort4 pk;
                    pk.x = f2bf(acc[tt][nf][0] + bsv);
                    pk.y = f2bf(acc[tt][nf][1] + bsv);
                    pk.z = f2bf(acc[tt][nf][2] + bsv);
                    pk.w = f2bf(acc[tt][nf][3] + bsv);
                    *(ushort4*)&vT[(size_t)bt * (256 * 4096) + (size_t)col * 4096 + hw0] = pk;
                }
            } else {
                ushort* out = which == 0 ? q : k;
                float scale = which == 0 ? QSCALE : 1.0f;
#pragma unroll
                for (int nf = 0; nf < 4; ++nf) {
                    int col = (nf0 + nf) * 16 + lq;
                    float bsv = bias[col];
#pragma unroll
                    for (int r = 0; r < 4; ++r) {
                        int rr = m0 + lg * 4 + r;
                        out[(size_t)rr * 256 + col] = f2bf((acc[tt][nf][r] + bsv) * scale);
                    }
                }
            }
        }
    }
}

// ---------------- flash attention: 4-wave blocks, KVBLK=32, 2 blocks/CU, split-KV x2 ---------
// R20/R22 config VERBATIM (best measured: ~159us).
__global__ __launch_bounds__(256, 2) void flash_kernel(const ushort* __restrict__ q,
                                                       const ushort* __restrict__ kk,
                                                       const ushort* __restrict__ vT,
                                                       ushort* __restrict__ Opart,
                                                       float* __restrict__ ml) {
    extern __shared__ char smem[];
    const int t = threadIdx.x, lane = t & 63, wvi = t >> 6;   // 4 waves
    const int l31 = lane & 31, hi = lane >> 5;
    const int bid = blockIdx.x;
    const int batch = bid & 7, half = (bid >> 3) & 1, qt = bid >> 4;   // qt 0..31
    const size_t bb = (size_t)batch * HW * Cc;
    const int t0 = half * 64;   // first kv tile (of 128 tiles of 32 kv)

    const int qbase = qt * 128 + wvi * 32;
    bf8_t qf[16];
    {
        const ushort* qrow = q + bb + (size_t)(qbase + l31) * Cc + hi * 8;
#pragma unroll
        for (int ks = 0; ks < 16; ++ks) qf[ks] = *(const bf8_t*)(qrow + ks * 16);
    }

    f32x16 o[8];
#pragma unroll
    for (int i = 0; i < 8; ++i) o[i] = (f32x16)0.f;
    float l_i = 0.f;

    const ushort* ksrc_b = kk + bb;
    const ushort* vsrc_b = vT + (size_t)batch * (256 * 4096);

    auto stage = [&](int kt, int bufsel) {
        const ushort* ks_ = ksrc_b + (size_t)kt * 32 * 256;
        const ushort* vs_ = vsrc_b + kt * 32;
        char* kd = smem + bufsel * 16384;
        char* vd = smem + 32768 + bufsel * 16384;
#pragma unroll
        for (int i = 0; i < 4; ++i) {
            int n = i * 256 + t;
            int kr = n >> 5;
            int c = (n & 31) ^ (kr & 7);
            gload16(ks_ + kr * 256 + c * 8, kd + n * 16);
        }
#pragma unroll
        for (int i = 0; i < 4; ++i) {
            int n = i * 256 + t;
            int d = n >> 2;
            int c = (n & 3) ^ ((d >> 2) & 3);
            gload16(vs_ + (size_t)d * HW + c * 8, vd + n * 16);
        }
    };

    stage(t0, 0);
    asm volatile("s_waitcnt vmcnt(0)" ::: "memory");
    __builtin_amdgcn_s_barrier();
    __builtin_amdgcn_sched_barrier(0);

    for (int it = 0; it < 64; ++it) {
        const int cur = it & 1;
        if (it + 1 < 64) stage(t0 + it + 1, cur ^ 1);

        const char* Kb = smem + cur * 16384;
        const char* Vb = smem + 32768 + cur * 16384;

        f32x16 sa = (f32x16)(-8.0f);
        __builtin_amdgcn_s_setprio(1);
#pragma unroll
        for (int ks = 0; ks < 16; ++ks) {
            int chunk = 2 * ks + hi;
            int sw = (chunk ^ (l31 & 7)) * 16;
            bf8_t kf = *(const bf8_t*)(Kb + l31 * 512 + sw);
            sa = __builtin_amdgcn_mfma_f32_32x32x16_bf16(kf, qf[ks], sa, 0, 0, 0);
        }
        __builtin_amdgcn_s_setprio(0);

#pragma unroll
        for (int s = 0; s < 2; ++s) {
            int b8 = s * 8;
            float p0 = fexp2(sa[b8 + 0]), p1 = fexp2(sa[b8 + 1]);
            float p2 = fexp2(sa[b8 + 2]), p3 = fexp2(sa[b8 + 3]);
            float p4 = fexp2(sa[b8 + 4]), p5 = fexp2(sa[b8 + 5]);
            float p6 = fexp2(sa[b8 + 6]), p7 = fexp2(sa[b8 + 7]);
            l_i += ((p0 + p1) + (p2 + p3)) + ((p4 + p5) + (p6 + p7));
            uint32_t w0 = cvtpk(p0, p1), w1 = cvtpk(p2, p3);
            uint32_t w2 = cvtpk(p4, p5), w3 = cvtpk(p6, p7);
            asm volatile("v_permlane32_swap_b32 %0, %1" : "+v"(w0), "+v"(w2));
            asm volatile("v_permlane32_swap_b32 %0, %1" : "+v"(w1), "+v"(w3));
            union { uint32_t u[4]; bf8_t v; } pa;
            pa.u[0] = w0; pa.u[1] = w1; pa.u[2] = w2; pa.u[3] = w3;

            __builtin_amdgcn_s_setprio(1);
#pragma unroll
            for (int nt = 0; nt < 8; ++nt) {
                int d = nt * 32 + l31;
                int ch = 2 * s + hi;
                bf8_t vf = *(const bf8_t*)(Vb + d * 64 + ((ch ^ ((d >> 2) & 3)) * 16));
                o[nt] = __builtin_amdgcn_mfma_f32_32x32x16_bf16(pa.v, vf, o[nt], 0, 0, 0);
            }
            __builtin_amdgcn_s_setprio(0);
        }

        if (it + 1 < 64) {
            asm volatile("s_waitcnt vmcnt(0)" ::: "memory");
            __builtin_amdgcn_s_barrier();
            __builtin_amdgcn_sched_barrier(0);
        }
    }

    float l_row = l_i + __shfl_xor(l_i, 32);
    ushort* op = Opart + (size_t)bid * (128 * 256) + (size_t)(wvi * 32) * 256;
#pragma unroll
    for (int nt = 0; nt < 8; ++nt) {
#pragma unroll
        for (int r = 0; r < 16; ++r) {
            int qrow = (r & 3) + 8 * (r >> 2) + 4 * hi;
            op[(size_t)qrow * 256 + nt * 32 + l31] = f2bf(o[nt][r]);
        }
    }
    if (lane < 32) {
        ml[(size_t)bid * 128 + wvi * 32 + l31] = l_row;
    }
}

// ---------------- fused combine + proj GEMM + bias + residual (wave = 32 rows x 128 cols) ----
__global__ __launch_bounds__(256) void projc_gemm(const ushort* __restrict__ Opart,
                                                  const float* __restrict__ ml,
                                                  const ushort* __restrict__ wT,
                                                  const float* __restrict__ bp,
                                                  const float* __restrict__ x,
                                                  float* __restrict__ outp) {
    int lane = threadIdx.x & 63, wvi = threadIdx.x >> 6;
    int lq = lane & 15, lg = lane >> 4;
    int rowhalf = wvi >> 1, nf0 = (wvi & 1) * 8;
    int m0b = blockIdx.x * 64 + rowhalf * 32;

    bf8_t a[2][8];
#pragma unroll
    for (int tt = 0; tt < 2; ++tt) {
        int row = m0b + tt * 16 + lq;
        int batch = row >> 12, rr = row & 4095;
        int qt = rr >> 7, rit = rr & 127;
        int blkA = batch + 16 * qt, blkB = blkA + 8;
        float la = ml[(size_t)blkA * 128 + rit];
        float lb = ml[(size_t)blkB * 128 + rit];
        float inv = 1.0f / (la + lb);
        const ushort* Arow = Opart + (size_t)blkA * 32768 + (size_t)rit * 256 + lg * 8;
        const ushort* Brow = Opart + (size_t)blkB * 32768 + (size_t)rit * 256 + lg * 8;
#pragma unroll
        for (int ks = 0; ks < 8; ++ks) {
            bf8_t fa = *(const bf8_t*)(Arow + ks * 32);
            bf8_t fb = *(const bf8_t*)(Brow + ks * 32);
            bf8_t mg;
#pragma unroll
            for (int j = 0; j < 8; ++j)
                mg[j] = (short)f2bf((bf2f((ushort)fa[j]) + bf2f((ushort)fb[j])) * inv);
            a[tt][ks] = mg;
        }
    }

    f4_t acc[2][8];
#pragma unroll
    for (int tt = 0; tt < 2; ++tt)
#pragma unroll
        for (int i = 0; i < 8; ++i) acc[tt][i] = (f4_t)0.f;

    const ushort* brow = wT + (size_t)(nf0 * 16 + lq) * 256 + lg * 8;
#pragma unroll
    for (int nf = 0; nf < 8; ++nf) {
#pragma unroll
        for (int ks = 0; ks < 8; ++ks) {
            bf8_t bfr = *(const bf8_t*)(brow + nf * 16 * 256 + ks * 32);
            acc[0][nf] = __builtin_amdgcn_mfma_f32_16x16x32_bf16(a[0][ks], bfr, acc[0][nf], 0, 0, 0);
            acc[1][nf] = __builtin_amdgcn_mfma_f32_16x16x32_bf16(a[1][ks], bfr, acc[1][nf], 0, 0, 0);
        }
    }
#pragma unroll
    for (int tt = 0; tt < 2; ++tt) {
#pragma unroll
        for (int nf = 0; nf < 8; ++nf) {
            int col = (nf0 + nf) * 16 + lq;
            float bsv = bp[col];
#pragma unroll
            for (int r = 0; r < 4; ++r) {
                size_t idx = (size_t)(m0b + tt * 16 + lg * 4 + r) * 256 + col;
                outp[idx] = x[idx] + acc[tt][nf][r] + bsv;
            }
        }
    }
}

extern "C" void kernel_launch(void* const* d_in, const int* in_sizes, int n_in,
                              void* d_out, int out_size, void* d_ws, size_t ws_size,
                              hipStream_t stream) {
    const float* x  = (const float*)d_in[0];
    const float* gs = (const float*)d_in[1];
    const float* gb = (const float*)d_in[2];
    const float* wq = (const float*)d_in[3];
    const float* bq = (const float*)d_in[4];
    const float* wk = (const float*)d_in[5];
    const float* bk = (const float*)d_in[6];
    const float* wv = (const float*)d_in[7];
    const float* bv = (const float*)d_in[8];
    const float* wp = (const float*)d_in[9];
    const float* bp = (const float*)d_in[10];
    float* out = (float*)d_out;

    char* ws = (char*)d_ws;
    ushort* wT    = (ushort*)ws;                         // 512 KB
    float*  psum  = (float*)(ws + 512 * 1024);           // 64 KB
    float*  psumsq= (float*)(ws + 576 * 1024);           // 64 KB
    float*  stats = (float*)(ws + 640 * 1024);           // 2 KB
    ushort* qb    = (ushort*)(ws + (size_t)17 * (1 << 20));
    ushort* kb    = (ushort*)(ws + (size_t)33 * (1 << 20));
    ushort* vTb   = (ushort*)(ws + (size_t)49 * (1 << 20));   // V transposed [b][d][hw]
    ushort* Opart = (ushort*)(ws + (size_t)65 * (1 << 20));   // 32 MB: 512 x 128 x 256 bf16
    float*  mlb   = (float*)(ws + (size_t)97 * (1 << 20));    // 256 KB: 512 x 128 float

    prep_kernel<<<768, 256, 0, stream>>>(x, psum, psumsq, wq, wk, wv, wp, wT);
    gn_stats<<<1, 256, 0, stream>>>(psum, psumsq, stats);
    qkv_gn<<<512, 256, 0, stream>>>(x, stats, gs, gb, wT, bq, bk, bv, qb, kb, vTb);

    hipFuncSetAttribute(reinterpret_cast<const void*>(flash_kernel),
                        hipFuncAttributeMaxDynamicSharedMemorySize, 65536);
    flash_kernel<<<512, 256, 65536, stream>>>(qb, kb, vTb, Opart, mlb);

    projc_gemm<<<512, 256, 0, stream>>>(Opart, mlb, wT + 3 * 65536, bp, x, out);
}

// Round 24
// 235.411 us; speedup vs baseline: 1.1923x; 1.0224x over previous
//
#include <hip/hip_runtime.h>
#include <hip/hip_bf16.h>
#include <stdint.h>

// ---- problem constants ----
static constexpr int HW = 4096;     // 64*64
static constexpr int Cc = 256;
static constexpr int Gg = 32;
static constexpr float EPSV = 1e-6f;
static constexpr float QSCALE = 0.0625f * 1.44269504f;   // c^-0.5 * log2(e): softmax in exp2 domain

typedef __attribute__((ext_vector_type(8))) short bf8_t;     // 8 bf16 (4 VGPR)
typedef __attribute__((ext_vector_type(4))) float f4_t;      // 16x16 mfma acc
typedef __attribute__((ext_vector_type(16))) float f32x16;   // 32x32 mfma acc

__device__ __forceinline__ ushort f2bf(float x) {
    union { float f; uint32_t u; } v; v.f = x;
    uint32_t r = v.u + 0x7FFFu + ((v.u >> 16) & 1u);
    return (ushort)(r >> 16);
}
__device__ __forceinline__ float bf2f(ushort u) {
    union { uint32_t u; float f; } v; v.u = ((uint32_t)u) << 16;
    return v.f;
}
__device__ __forceinline__ uint32_t cvtpk(float lo, float hi_) {
    uint32_t r;
    asm volatile("v_cvt_pk_bf16_f32 %0, %1, %2" : "=v"(r) : "v"(lo), "v"(hi_));
    return r;
}
__device__ __forceinline__ float fexp2(float x) {   // raw v_exp_f32
    float r;
    asm("v_exp_f32 %0, %1" : "=v"(r) : "v"(x));
    return r;
}

// async global->LDS DMA, 16B per lane; lds dest is wave-uniform base (+lane*16 by HW)
__device__ __forceinline__ void gload16(const void* g, void* l) {
    __builtin_amdgcn_global_load_lds((const __attribute__((address_space(1))) void*)g,
                                     (__attribute__((address_space(3))) void*)l, 16, 0, 0);
}

// ---------------- prep: GN partial sums (blocks 0..511) + weight transpose (blocks 512..767) --
// wT[which][d][c] = bf16(w[c][d])
__global__ void prep_kernel(const float* __restrict__ x, float* __restrict__ psum,
                            float* __restrict__ psumsq,
                            const float* __restrict__ wq, const float* __restrict__ wk,
                            const float* __restrict__ wv, const float* __restrict__ wp,
                            ushort* __restrict__ wT) {
    int bx = blockIdx.x;
    if (bx < 512) {
        int slice = bx & 63;
        int b = bx >> 6;
        int c = threadIdx.x;
        const float* xp = x + ((size_t)b * HW + (size_t)slice * 64) * Cc + c;
        float s = 0.f, sq = 0.f;
        for (int p = 0; p < 64; ++p) { float v = xp[(size_t)p * Cc]; s += v; sq += v * v; }
        for (int m = 1; m < 8; m <<= 1) { s += __shfl_xor(s, m); sq += __shfl_xor(sq, m); }
        if ((c & 7) == 0) {
            int g = c >> 3;
            psum[(b * Gg + g) * 64 + slice] = s;
            psumsq[(b * Gg + g) * 64 + slice] = sq;
        }
    } else {
        int base = (bx - 512) * 1024 + threadIdx.x * 4;   // 4 consecutive c, same d
        int which = base >> 16;
        const float* w = which == 0 ? wq : which == 1 ? wk : which == 2 ? wv : wp;
        int rem = base & 65535;
        int d = rem >> 8, c = rem & 255;
        ushort4 o;
        o.x = f2bf(w[(c + 0) * 256 + d]);
        o.y = f2bf(w[(c + 1) * 256 + d]);
        o.z = f2bf(w[(c + 2) * 256 + d]);
        o.w = f2bf(w[(c + 3) * 256 + d]);
        *(ushort4*)&wT[which * 65536 + d * 256 + c] = o;
    }
}

__global__ void gn_stats(const float* __restrict__ psum, const float* __restrict__ psumsq,
                         float* __restrict__ stats) {
    int t = threadIdx.x;  // 256 = b*32+g
    float s = 0.f, sq = 0.f;
    for (int i = 0; i < 64; ++i) { s += psum[t * 64 + i]; sq += psumsq[t * 64 + i]; }
    float mean = s * (1.0f / 32768.0f);
    float var = sq * (1.0f / 32768.0f) - mean * mean;
    stats[t * 2] = mean;
    stats[t * 2 + 1] = rsqrtf(var + EPSV);
}

// ---------------- fused GN-normalize + QKV GEMM (LDS-staged normalize, wave = 64r x 64c) ----
__global__ __launch_bounds__(256) void qkv_gn(const float* __restrict__ x, const float* __restrict__ stats,
                                              const float* __restrict__ gs, const float* __restrict__ gb,
                                              const ushort* __restrict__ wT,
                                              const float* __restrict__ bq, const float* __restrict__ bk,
                                              const float* __restrict__ bv,
                                              ushort* __restrict__ q, ushort* __restrict__ k,
                                              ushort* __restrict__ vT) {
    __shared__ __align__(16) char sm[64 * 528];
    int t = threadIdx.x;
    int lane = t & 63, wvi = t >> 6;
    int lq = lane & 15, lg = lane >> 4;
    int nf0 = wvi * 4;                  // wave's 4 col-tiles (64 cols)
    int m0b = blockIdx.x * 64;          // block's 64 rows

    // ---- phase 1: normalize 64 rows once into LDS ----
    {
        int row = t >> 2, q4 = t & 3;            // 64 els: cols q4*64 .. +63
        int xrow = m0b + row;
        int batch = xrow >> 12;
        const float* xr = x + (size_t)xrow * 256;
        char* lrow = sm + row * 528;
#pragma unroll
        for (int i = 0; i < 8; ++i) {
            int c0 = q4 * 64 + i * 8;
            int g = c0 >> 3;
            float2 st = *(const float2*)&stats[(batch * Gg + g) * 2];
            float4 v0 = *(const float4*)&xr[c0];
            float4 v1 = *(const float4*)&xr[c0 + 4];
            float4 s0 = *(const float4*)&gs[c0];
            float4 s1 = *(const float4*)&gs[c0 + 4];
            float4 b0 = *(const float4*)&gb[c0];
            float4 b1 = *(const float4*)&gb[c0 + 4];
            union { ushort u[8]; uint4 v; } pk;
            pk.u[0] = f2bf((v0.x - st.x) * st.y * s0.x + b0.x);
            pk.u[1] = f2bf((v0.y - st.x) * st.y * s0.y + b0.y);
            pk.u[2] = f2bf((v0.z - st.x) * st.y * s0.z + b0.z);
            pk.u[3] = f2bf((v0.w - st.x) * st.y * s0.w + b0.w);
            pk.u[4] = f2bf((v1.x - st.x) * st.y * s1.x + b1.x);
            pk.u[5] = f2bf((v1.y - st.x) * st.y * s1.y + b1.y);
            pk.u[6] = f2bf((v1.z - st.x) * st.y * s1.z + b1.z);
            pk.u[7] = f2bf((v1.w - st.x) * st.y * s1.w + b1.w);
            *(uint4*)(lrow + c0 * 2) = pk.v;
        }
    }
    __syncthreads();

    // ---- phase 2: load A-fragments from LDS (once), then 3 GEMMs ----
    bf8_t a[4][8];
#pragma unroll
    for (int tt = 0; tt < 4; ++tt)
#pragma unroll
        for (int ks = 0; ks < 8; ++ks)
            a[tt][ks] = *(const bf8_t*)(sm + (tt * 16 + lq) * 528 + (ks * 32 + lg * 8) * 2);

#pragma unroll
    for (int which = 0; which < 3; ++which) {
        const ushort* w = wT + which * 65536;
        const float* bias = which == 0 ? bq : which == 1 ? bk : bv;

        f4_t acc[4][4];
#pragma unroll
        for (int tt = 0; tt < 4; ++tt)
#pragma unroll
            for (int i = 0; i < 4; ++i) acc[tt][i] = (f4_t)0.f;

        const ushort* brow = w + (size_t)(nf0 * 16 + lq) * 256 + lg * 8;
#pragma unroll
        for (int nf = 0; nf < 4; ++nf) {
#pragma unroll
            for (int ks = 0; ks < 8; ++ks) {
                bf8_t bfr = *(const bf8_t*)(brow + nf * 16 * 256 + ks * 32);
                acc[0][nf] = __builtin_amdgcn_mfma_f32_16x16x32_bf16(a[0][ks], bfr, acc[0][nf], 0, 0, 0);
                acc[1][nf] = __builtin_amdgcn_mfma_f32_16x16x32_bf16(a[1][ks], bfr, acc[1][nf], 0, 0, 0);
                acc[2][nf] = __builtin_amdgcn_mfma_f32_16x16x32_bf16(a[2][ks], bfr, acc[2][nf], 0, 0, 0);
                acc[3][nf] = __builtin_amdgcn_mfma_f32_16x16x32_bf16(a[3][ks], bfr, acc[3][nf], 0, 0, 0);
            }
        }
#pragma unroll
        for (int tt = 0; tt < 4; ++tt) {
            int m0 = m0b + tt * 16;
            if (which == 2) {
                int bt = m0 >> 12;
                int hw0 = (m0 & 4095) + lg * 4;
#pragma unroll
                for (int nf = 0; nf < 4; ++nf) {
                    int col = (nf0 + nf) * 16 + lq;
                    float bsv = bias[col];
                    ushort4 pk;
                    pk.x = f2bf(acc[tt][nf][0] + bsv);
                    pk.y = f2bf(acc[tt][nf][1] + bsv);
                    pk.z = f2bf(acc[tt][nf][2] + bsv);
                    pk.w = f2bf(acc[tt][nf][3] + bsv);
                    *(ushort4*)&vT[(size_t)bt * (256 * 4096) + (size_t)col * 4096 + hw0] = pk;
                }
            } else {
                ushort* out = which == 0 ? q : k;
                float scale = which == 0 ? QSCALE : 1.0f;
#pragma unroll
                for (int nf = 0; nf < 4; ++nf) {
                    int col = (nf0 + nf) * 16 + lq;
                    float bsv = bias[col];
#pragma unroll
                    for (int r = 0; r < 4; ++r) {
                        int rr = m0 + lg * 4 + r;
                        out[(size_t)rr * 256 + col] = f2bf((acc[tt][nf][r] + bsv) * scale);
                    }
                }
            }
        }
    }
}

// ---------------- flash attention: 4-wave blocks, KVBLK=32, 2 blocks/CU, split-KV x2 ---------
// R20/R22 config VERBATIM (best measured: ~160us).
__global__ __launch_bounds__(256, 2) void flash_kernel(const ushort* __restrict__ q,
                                                       const ushort* __restrict__ kk,
                                                       const ushort* __restrict__ vT,
                                                       ushort* __restrict__ Opart,
                                                       float* __restrict__ ml) {
    extern __shared__ char smem[];
    const int t = threadIdx.x, lane = t & 63, wvi = t >> 6;   // 4 waves
    const int l31 = lane & 31, hi = lane >> 5;
    const int bid = blockIdx.x;
    const int batch = bid & 7, half = (bid >> 3) & 1, qt = bid >> 4;   // qt 0..31
    const size_t bb = (size_t)batch * HW * Cc;
    const int t0 = half * 64;   // first kv tile (of 128 tiles of 32 kv)

    const int qbase = qt * 128 + wvi * 32;
    bf8_t qf[16];
    {
        const ushort* qrow = q + bb + (size_t)(qbase + l31) * Cc + hi * 8;
#pragma unroll
        for (int ks = 0; ks < 16; ++ks) qf[ks] = *(const bf8_t*)(qrow + ks * 16);
    }

    f32x16 o[8];
#pragma unroll
    for (int i = 0; i < 8; ++i) o[i] = (f32x16)0.f;
    float l_i = 0.f;

    const ushort* ksrc_b = kk + bb;
    const ushort* vsrc_b = vT + (size_t)batch * (256 * 4096);

    auto stage = [&](int kt, int bufsel) {
        const ushort* ks_ = ksrc_b + (size_t)kt * 32 * 256;
        const ushort* vs_ = vsrc_b + kt * 32;
        char* kd = smem + bufsel * 16384;
        char* vd = smem + 32768 + bufsel * 16384;
#pragma unroll
        for (int i = 0; i < 4; ++i) {
            int n = i * 256 + t;
            int kr = n >> 5;
            int c = (n & 31) ^ (kr & 7);
            gload16(ks_ + kr * 256 + c * 8, kd + n * 16);
        }
#pragma unroll
        for (int i = 0; i < 4; ++i) {
            int n = i * 256 + t;
            int d = n >> 2;
            int c = (n & 3) ^ ((d >> 2) & 3);
            gload16(vs_ + (size_t)d * HW + c * 8, vd + n * 16);
        }
    };

    stage(t0, 0);
    asm volatile("s_waitcnt vmcnt(0)" ::: "memory");
    __builtin_amdgcn_s_barrier();
    __builtin_amdgcn_sched_barrier(0);

    for (int it = 0; it < 64; ++it) {
        const int cur = it & 1;
        if (it + 1 < 64) stage(t0 + it + 1, cur ^ 1);

        const char* Kb = smem + cur * 16384;
        const char* Vb = smem + 32768 + cur * 16384;

        f32x16 sa = (f32x16)(-8.0f);
        __builtin_amdgcn_s_setprio(1);
#pragma unroll
        for (int ks = 0; ks < 16; ++ks) {
            int chunk = 2 * ks + hi;
            int sw = (chunk ^ (l31 & 7)) * 16;
            bf8_t kf = *(const bf8_t*)(Kb + l31 * 512 + sw);
            sa = __builtin_amdgcn_mfma_f32_32x32x16_bf16(kf, qf[ks], sa, 0, 0, 0);
        }
        __builtin_amdgcn_s_setprio(0);

#pragma unroll
        for (int s = 0; s < 2; ++s) {
            int b8 = s * 8;
            float p0 = fexp2(sa[b8 + 0]), p1 = fexp2(sa[b8 + 1]);
            float p2 = fexp2(sa[b8 + 2]), p3 = fexp2(sa[b8 + 3]);
            float p4 = fexp2(sa[b8 + 4]), p5 = fexp2(sa[b8 + 5]);
            float p6 = fexp2(sa[b8 + 6]), p7 = fexp2(sa[b8 + 7]);
            l_i += ((p0 + p1) + (p2 + p3)) + ((p4 + p5) + (p6 + p7));
            uint32_t w0 = cvtpk(p0, p1), w1 = cvtpk(p2, p3);
            uint32_t w2 = cvtpk(p4, p5), w3 = cvtpk(p6, p7);
            asm volatile("v_permlane32_swap_b32 %0, %1" : "+v"(w0), "+v"(w2));
            asm volatile("v_permlane32_swap_b32 %0, %1" : "+v"(w1), "+v"(w3));
            union { uint32_t u[4]; bf8_t v; } pa;
            pa.u[0] = w0; pa.u[1] = w1; pa.u[2] = w2; pa.u[3] = w3;

            __builtin_amdgcn_s_setprio(1);
#pragma unroll
            for (int nt = 0; nt < 8; ++nt) {
                int d = nt * 32 + l31;
                int ch = 2 * s + hi;
                bf8_t vf = *(const bf8_t*)(Vb + d * 64 + ((ch ^ ((d >> 2) & 3)) * 16));
                o[nt] = __builtin_amdgcn_mfma_f32_32x32x16_bf16(pa.v, vf, o[nt], 0, 0, 0);
            }
            __builtin_amdgcn_s_setprio(0);
        }

        if (it + 1 < 64) {
            asm volatile("s_waitcnt vmcnt(0)" ::: "memory");
            __builtin_amdgcn_s_barrier();
            __builtin_amdgcn_sched_barrier(0);
        }
    }

    float l_row = l_i + __shfl_xor(l_i, 32);
    ushort* op = Opart + (size_t)bid * (128 * 256) + (size_t)(wvi * 32) * 256;
#pragma unroll
    for (int nt = 0; nt < 8; ++nt) {
#pragma unroll
        for (int r = 0; r < 16; ++r) {
            int qrow = (r & 3) + 8 * (r >> 2) + 4 * hi;
            op[(size_t)qrow * 256 + nt * 32 + l31] = f2bf(o[nt][r]);
        }
    }
    if (lane < 32) {
        ml[(size_t)bid * 128 + wvi * 32 + l31] = l_row;
    }
}

// ---------------- fused combine + proj GEMM (LDS-staged combine, wave = 64r x 64c) ----------
// Phase 1: block combines its 64 rows ONCE ((OA+OB)/(lA+lB) -> bf16 LDS, pitch 528).
// Phase 2: proj GEMM with nf-quarter wave split (1/4 of wp per wave), + bias + residual.
__global__ __launch_bounds__(256) void projc_gemm(const ushort* __restrict__ Opart,
                                                  const float* __restrict__ ml,
                                                  const ushort* __restrict__ wT,
                                                  const float* __restrict__ bp,
                                                  const float* __restrict__ x,
                                                  float* __restrict__ outp) {
    __shared__ __align__(16) char sm[64 * 528];
    int t = threadIdx.x;
    int lane = t & 63, wvi = t >> 6;
    int lq = lane & 15, lg = lane >> 4;
    int nf0 = wvi * 4;                  // wave's 4 col-tiles (64 cols)
    int m0b = blockIdx.x * 64;          // block's 64 rows

    // ---- phase 1: combine the block's 64 rows once into LDS ----
    {
        int row = t >> 2, q4 = t & 3;
        int xrow = m0b + row;
        int batch = xrow >> 12, rr = xrow & 4095;
        int qt = rr >> 7, rit = rr & 127;
        int blkA = batch + 16 * qt, blkB = blkA + 8;
        float la = ml[(size_t)blkA * 128 + rit];
        float lb = ml[(size_t)blkB * 128 + rit];
        float inv = 1.0f / (la + lb);
        const ushort* Arow = Opart + (size_t)blkA * 32768 + (size_t)rit * 256;
        const ushort* Brow = Opart + (size_t)blkB * 32768 + (size_t)rit * 256;
        char* lrow = sm + row * 528;
#pragma unroll
        for (int i = 0; i < 8; ++i) {
            int c0 = q4 * 64 + i * 8;
            bf8_t fa = *(const bf8_t*)(Arow + c0);
            bf8_t fb = *(const bf8_t*)(Brow + c0);
            union { ushort u[8]; uint4 v; } pk;
#pragma unroll
            for (int j = 0; j < 8; ++j)
                pk.u[j] = f2bf((bf2f((ushort)fa[j]) + bf2f((ushort)fb[j])) * inv);
            *(uint4*)(lrow + c0 * 2) = pk.v;
        }
    }
    __syncthreads();

    // ---- phase 2: a[4][8] from LDS, proj GEMM (wave = 64 rows x 64 cols) ----
    bf8_t a[4][8];
#pragma unroll
    for (int tt = 0; tt < 4; ++tt)
#pragma unroll
        for (int ks = 0; ks < 8; ++ks)
            a[tt][ks] = *(const bf8_t*)(sm + (tt * 16 + lq) * 528 + (ks * 32 + lg * 8) * 2);

    f4_t acc[4][4];
#pragma unroll
    for (int tt = 0; tt < 4; ++tt)
#pragma unroll
        for (int i = 0; i < 4; ++i) acc[tt][i] = (f4_t)0.f;

    const ushort* brow = wT + (size_t)(nf0 * 16 + lq) * 256 + lg * 8;
#pragma unroll
    for (int nf = 0; nf < 4; ++nf) {
#pragma unroll
        for (int ks = 0; ks < 8; ++ks) {
            bf8_t bfr = *(const bf8_t*)(brow + nf * 16 * 256 + ks * 32);
            acc[0][nf] = __builtin_amdgcn_mfma_f32_16x16x32_bf16(a[0][ks], bfr, acc[0][nf], 0, 0, 0);
            acc[1][nf] = __builtin_amdgcn_mfma_f32_16x16x32_bf16(a[1][ks], bfr, acc[1][nf], 0, 0, 0);
            acc[2][nf] = __builtin_amdgcn_mfma_f32_16x16x32_bf16(a[2][ks], bfr, acc[2][nf], 0, 0, 0);
            acc[3][nf] = __builtin_amdgcn_mfma_f32_16x16x32_bf16(a[3][ks], bfr, acc[3][nf], 0, 0, 0);
        }
    }
#pragma unroll
    for (int tt = 0; tt < 4; ++tt) {
#pragma unroll
        for (int nf = 0; nf < 4; ++nf) {
            int col = (nf0 + nf) * 16 + lq;
            float bsv = bp[col];
#pragma unroll
            for (int r = 0; r < 4; ++r) {
                size_t idx = (size_t)(m0b + tt * 16 + lg * 4 + r) * 256 + col;
                outp[idx] = x[idx] + acc[tt][nf][r] + bsv;
            }
        }
    }
}

extern "C" void kernel_launch(void* const* d_in, const int* in_sizes, int n_in,
                              void* d_out, int out_size, void* d_ws, size_t ws_size,
                              hipStream_t stream) {
    const float* x  = (const float*)d_in[0];
    const float* gs = (const float*)d_in[1];
    const float* gb = (const float*)d_in[2];
    const float* wq = (const float*)d_in[3];
    const float* bq = (const float*)d_in[4];
    const float* wk = (const float*)d_in[5];
    const float* bk = (const float*)d_in[6];
    const float* wv = (const float*)d_in[7];
    const float* bv = (const float*)d_in[8];
    const float* wp = (const float*)d_in[9];
    const float* bp = (const float*)d_in[10];
    float* out = (float*)d_out;

    char* ws = (char*)d_ws;
    ushort* wT    = (ushort*)ws;                         // 512 KB
    float*  psum  = (float*)(ws + 512 * 1024);           // 64 KB
    float*  psumsq= (float*)(ws + 576 * 1024);           // 64 KB
    float*  stats = (float*)(ws + 640 * 1024);           // 2 KB
    ushort* qb    = (ushort*)(ws + (size_t)17 * (1 << 20));
    ushort* kb    = (ushort*)(ws + (size_t)33 * (1 << 20));
    ushort* vTb   = (ushort*)(ws + (size_t)49 * (1 << 20));   // V transposed [b][d][hw]
    ushort* Opart = (ushort*)(ws + (size_t)65 * (1 << 20));   // 32 MB: 512 x 128 x 256 bf16
    float*  mlb   = (float*)(ws + (size_t)97 * (1 << 20));    // 256 KB: 512 x 128 float

    prep_kernel<<<768, 256, 0, stream>>>(x, psum, psumsq, wq, wk, wv, wp, wT);
    gn_stats<<<1, 256, 0, stream>>>(psum, psumsq, stats);
    qkv_gn<<<512, 256, 0, stream>>>(x, stats, gs, gb, wT, bq, bk, bv, qb, kb, vTb);

    hipFuncSetAttribute(reinterpret_cast<const void*>(flash_kernel),
                        hipFuncAttributeMaxDynamicSharedMemorySize, 65536);
    flash_kernel<<<512, 256, 65536, stream>>>(qb, kb, vTb, Opart, mlb);

    projc_gemm<<<512, 256, 0, stream>>>(Opart, mlb, wT + 3 * 65536, bp, x, out);
}

// Round 25
// 228.921 us; speedup vs baseline: 1.2261x; 1.0284x over previous
//
#include <hip/hip_runtime.h>
#include <hip/hip_bf16.h>
#include <stdint.h>

// ---- problem constants ----
static constexpr int HW = 4096;     // 64*64
static constexpr int Cc = 256;
static constexpr int Gg = 32;
static constexpr float EPSV = 1e-6f;
static constexpr float QSCALE = 0.0625f * 1.44269504f;   // c^-0.5 * log2(e): softmax in exp2 domain

typedef __attribute__((ext_vector_type(8))) short bf8_t;     // 8 bf16 (4 VGPR)
typedef __attribute__((ext_vector_type(4))) float f4_t;      // 16x16 mfma acc
typedef __attribute__((ext_vector_type(16))) float f32x16;   // 32x32 mfma acc

__device__ __forceinline__ ushort f2bf(float x) {
    union { float f; uint32_t u; } v; v.f = x;
    uint32_t r = v.u + 0x7FFFu + ((v.u >> 16) & 1u);
    return (ushort)(r >> 16);
}
__device__ __forceinline__ float bf2f(ushort u) {
    union { uint32_t u; float f; } v; v.u = ((uint32_t)u) << 16;
    return v.f;
}
__device__ __forceinline__ uint32_t cvtpk(float lo, float hi_) {
    uint32_t r;
    asm volatile("v_cvt_pk_bf16_f32 %0, %1, %2" : "=v"(r) : "v"(lo), "v"(hi_));
    return r;
}
__device__ __forceinline__ float fexp2(float x) {   // raw v_exp_f32
    float r;
    asm("v_exp_f32 %0, %1" : "=v"(r) : "v"(x));
    return r;
}

// async global->LDS DMA, 16B per lane; lds dest is wave-uniform base (+lane*16 by HW)
__device__ __forceinline__ void gload16(const void* g, void* l) {
    __builtin_amdgcn_global_load_lds((const __attribute__((address_space(1))) void*)g,
                                     (__attribute__((address_space(3))) void*)l, 16, 0, 0);
}

// ---------------- prep: GN partial sums (blocks 0..511) + weight transpose (blocks 512..767) --
// wT[which][d][c] = bf16(w[c][d])
__global__ void prep_kernel(const float* __restrict__ x, float* __restrict__ psum,
                            float* __restrict__ psumsq,
                            const float* __restrict__ wq, const float* __restrict__ wk,
                            const float* __restrict__ wv, const float* __restrict__ wp,
                            ushort* __restrict__ wT) {
    int bx = blockIdx.x;
    if (bx < 512) {
        int slice = bx & 63;
        int b = bx >> 6;
        int c = threadIdx.x;
        const float* xp = x + ((size_t)b * HW + (size_t)slice * 64) * Cc + c;
        float s = 0.f, sq = 0.f;
        for (int p = 0; p < 64; ++p) { float v = xp[(size_t)p * Cc]; s += v; sq += v * v; }
        for (int m = 1; m < 8; m <<= 1) { s += __shfl_xor(s, m); sq += __shfl_xor(sq, m); }
        if ((c & 7) == 0) {
            int g = c >> 3;
            psum[(b * Gg + g) * 64 + slice] = s;
            psumsq[(b * Gg + g) * 64 + slice] = sq;
        }
    } else {
        int base = (bx - 512) * 1024 + threadIdx.x * 4;   // 4 consecutive c, same d
        int which = base >> 16;
        const float* w = which == 0 ? wq : which == 1 ? wk : which == 2 ? wv : wp;
        int rem = base & 65535;
        int d = rem >> 8, c = rem & 255;
        ushort4 o;
        o.x = f2bf(w[(c + 0) * 256 + d]);
        o.y = f2bf(w[(c + 1) * 256 + d]);
        o.z = f2bf(w[(c + 2) * 256 + d]);
        o.w = f2bf(w[(c + 3) * 256 + d]);
        *(ushort4*)&wT[which * 65536 + d * 256 + c] = o;
    }
}

// ---------------- fused GN-stats + GN-normalize + QKV GEMM ----------------
// Phase 0: block computes its batch's 32 (mean,rstd) pairs from the psum partials
// (psum/psumsq are 128KB total -> L2-resident across all 512 blocks).
// Phase 1: block normalizes its 64 rows ONCE into padded LDS (pitch 528B, bank-clean).
// Phase 2: waves load a[4][8] from LDS and run the 3 GEMMs (nf-quarter split).
__global__ __launch_bounds__(256) void qkv_gn(const float* __restrict__ x,
                                              const float* __restrict__ psum,
                                              const float* __restrict__ psumsq,
                                              const float* __restrict__ gs, const float* __restrict__ gb,
                                              const ushort* __restrict__ wT,
                                              const float* __restrict__ bq, const float* __restrict__ bk,
                                              const float* __restrict__ bv,
                                              ushort* __restrict__ q, ushort* __restrict__ k,
                                              ushort* __restrict__ vT) {
    __shared__ __align__(16) char sm[64 * 528];
    __shared__ float2 sstats[32];
    int t = threadIdx.x;
    int lane = t & 63, wvi = t >> 6;
    int lq = lane & 15, lg = lane >> 4;
    int nf0 = wvi * 4;                  // wave's 4 col-tiles (64 cols)
    int m0b = blockIdx.x * 64;          // block's 64 rows (single batch)
    int batch = blockIdx.x >> 6;

    // ---- phase 0: per-block GN stats (32 groups x 8 threads, 8 partials each) ----
    {
        int g = t >> 3, part = t & 7;
        const float* ps = psum + (size_t)(batch * Gg + g) * 64 + part * 8;
        const float* pq = psumsq + (size_t)(batch * Gg + g) * 64 + part * 8;
        float s = 0.f, sq = 0.f;
#pragma unroll
        for (int i = 0; i < 8; ++i) { s += ps[i]; sq += pq[i]; }
#pragma unroll
        for (int m = 1; m < 8; m <<= 1) { s += __shfl_xor(s, m); sq += __shfl_xor(sq, m); }
        if ((t & 7) == 0) {
            float mean = s * (1.0f / 32768.0f);
            float var = sq * (1.0f / 32768.0f) - mean * mean;
            sstats[g] = make_float2(mean, rsqrtf(var + EPSV));
        }
    }
    __syncthreads();

    // ---- phase 1: normalize 64 rows once into LDS ----
    {
        int row = t >> 2, q4 = t & 3;            // 64 els: cols q4*64 .. +63
        int xrow = m0b + row;
        const float* xr = x + (size_t)xrow * 256;
        char* lrow = sm + row * 528;
#pragma unroll
        for (int i = 0; i < 8; ++i) {
            int c0 = q4 * 64 + i * 8;
            int g = c0 >> 3;
            float2 st = sstats[g];
            float4 v0 = *(const float4*)&xr[c0];
            float4 v1 = *(const float4*)&xr[c0 + 4];
            float4 s0 = *(const float4*)&gs[c0];
            float4 s1 = *(const float4*)&gs[c0 + 4];
            float4 b0 = *(const float4*)&gb[c0];
            float4 b1 = *(const float4*)&gb[c0 + 4];
            union { ushort u[8]; uint4 v; } pk;
            pk.u[0] = f2bf((v0.x - st.x) * st.y * s0.x + b0.x);
            pk.u[1] = f2bf((v0.y - st.x) * st.y * s0.y + b0.y);
            pk.u[2] = f2bf((v0.z - st.x) * st.y * s0.z + b0.z);
            pk.u[3] = f2bf((v0.w - st.x) * st.y * s0.w + b0.w);
            pk.u[4] = f2bf((v1.x - st.x) * st.y * s1.x + b1.x);
            pk.u[5] = f2bf((v1.y - st.x) * st.y * s1.y + b1.y);
            pk.u[6] = f2bf((v1.z - st.x) * st.y * s1.z + b1.z);
            pk.u[7] = f2bf((v1.w - st.x) * st.y * s1.w + b1.w);
            *(uint4*)(lrow + c0 * 2) = pk.v;
        }
    }
    __syncthreads();

    // ---- phase 2: load A-fragments from LDS (once), then 3 GEMMs ----
    bf8_t a[4][8];
#pragma unroll
    for (int tt = 0; tt < 4; ++tt)
#pragma unroll
        for (int ks = 0; ks < 8; ++ks)
            a[tt][ks] = *(const bf8_t*)(sm + (tt * 16 + lq) * 528 + (ks * 32 + lg * 8) * 2);

#pragma unroll
    for (int which = 0; which < 3; ++which) {
        const ushort* w = wT + which * 65536;
        const float* bias = which == 0 ? bq : which == 1 ? bk : bv;

        f4_t acc[4][4];
#pragma unroll
        for (int tt = 0; tt < 4; ++tt)
#pragma unroll
            for (int i = 0; i < 4; ++i) acc[tt][i] = (f4_t)0.f;

        const ushort* brow = w + (size_t)(nf0 * 16 + lq) * 256 + lg * 8;
#pragma unroll
        for (int nf = 0; nf < 4; ++nf) {
#pragma unroll
            for (int ks = 0; ks < 8; ++ks) {
                bf8_t bfr = *(const bf8_t*)(brow + nf * 16 * 256 + ks * 32);
                acc[0][nf] = __builtin_amdgcn_mfma_f32_16x16x32_bf16(a[0][ks], bfr, acc[0][nf], 0, 0, 0);
                acc[1][nf] = __builtin_amdgcn_mfma_f32_16x16x32_bf16(a[1][ks], bfr, acc[1][nf], 0, 0, 0);
                acc[2][nf] = __builtin_amdgcn_mfma_f32_16x16x32_bf16(a[2][ks], bfr, acc[2][nf], 0, 0, 0);
                acc[3][nf] = __builtin_amdgcn_mfma_f32_16x16x32_bf16(a[3][ks], bfr, acc[3][nf], 0, 0, 0);
            }
        }
#pragma unroll
        for (int tt = 0; tt < 4; ++tt) {
            int m0 = m0b + tt * 16;
            if (which == 2) {
                int bt = m0 >> 12;
                int hw0 = (m0 & 4095) + lg * 4;
#pragma unroll
                for (int nf = 0; nf < 4; ++nf) {
                    int col = (nf0 + nf) * 16 + lq;
                    float bsv = bias[col];
                    ushort4 pk;
                    pk.x = f2bf(acc[tt][nf][0] + bsv);
                    pk.y = f2bf(acc[tt][nf][1] + bsv);
                    pk.z = f2bf(acc[tt][nf][2] + bsv);
                    pk.w = f2bf(acc[tt][nf][3] + bsv);
                    *(ushort4*)&vT[(size_t)bt * (256 * 4096) + (size_t)col * 4096 + hw0] = pk;
                }
            } else {
                ushort* out = which == 0 ? q : k;
                float scale = which == 0 ? QSCALE : 1.0f;
#pragma unroll
                for (int nf = 0; nf < 4; ++nf) {
                    int col = (nf0 + nf) * 16 + lq;
                    float bsv = bias[col];
#pragma unroll
                    for (int r = 0; r < 4; ++r) {
                        int rr = m0 + lg * 4 + r;
                        out[(size_t)rr * 256 + col] = f2bf((acc[tt][nf][r] + bsv) * scale);
                    }
                }
            }
        }
    }
}

// ---------------- flash attention: 4-wave blocks, KVBLK=32, 2 blocks/CU, split-KV x2 ---------
// R20/R22 config VERBATIM (best measured: ~160us).
__global__ __launch_bounds__(256, 2) void flash_kernel(const ushort* __restrict__ q,
                                                       const ushort* __restrict__ kk,
                                                       const ushort* __restrict__ vT,
                                                       ushort* __restrict__ Opart,
                                                       float* __restrict__ ml) {
    extern __shared__ char smem[];
    const int t = threadIdx.x, lane = t & 63, wvi = t >> 6;   // 4 waves
    const int l31 = lane & 31, hi = lane >> 5;
    const int bid = blockIdx.x;
    const int batch = bid & 7, half = (bid >> 3) & 1, qt = bid >> 4;   // qt 0..31
    const size_t bb = (size_t)batch * HW * Cc;
    const int t0 = half * 64;   // first kv tile (of 128 tiles of 32 kv)

    const int qbase = qt * 128 + wvi * 32;
    bf8_t qf[16];
    {
        const ushort* qrow = q + bb + (size_t)(qbase + l31) * Cc + hi * 8;
#pragma unroll
        for (int ks = 0; ks < 16; ++ks) qf[ks] = *(const bf8_t*)(qrow + ks * 16);
    }

    f32x16 o[8];
#pragma unroll
    for (int i = 0; i < 8; ++i) o[i] = (f32x16)0.f;
    float l_i = 0.f;

    const ushort* ksrc_b = kk + bb;
    const ushort* vsrc_b = vT + (size_t)batch * (256 * 4096);

    auto stage = [&](int kt, int bufsel) {
        const ushort* ks_ = ksrc_b + (size_t)kt * 32 * 256;
        const ushort* vs_ = vsrc_b + kt * 32;
        char* kd = smem + bufsel * 16384;
        char* vd = smem + 32768 + bufsel * 16384;
#pragma unroll
        for (int i = 0; i < 4; ++i) {
            int n = i * 256 + t;
            int kr = n >> 5;
            int c = (n & 31) ^ (kr & 7);
            gload16(ks_ + kr * 256 + c * 8, kd + n * 16);
        }
#pragma unroll
        for (int i = 0; i < 4; ++i) {
            int n = i * 256 + t;
            int d = n >> 2;
            int c = (n & 3) ^ ((d >> 2) & 3);
            gload16(vs_ + (size_t)d * HW + c * 8, vd + n * 16);
        }
    };

    stage(t0, 0);
    asm volatile("s_waitcnt vmcnt(0)" ::: "memory");
    __builtin_amdgcn_s_barrier();
    __builtin_amdgcn_sched_barrier(0);

    for (int it = 0; it < 64; ++it) {
        const int cur = it & 1;
        if (it + 1 < 64) stage(t0 + it + 1, cur ^ 1);

        const char* Kb = smem + cur * 16384;
        const char* Vb = smem + 32768 + cur * 16384;

        f32x16 sa = (f32x16)(-8.0f);
        __builtin_amdgcn_s_setprio(1);
#pragma unroll
        for (int ks = 0; ks < 16; ++ks) {
            int chunk = 2 * ks + hi;
            int sw = (chunk ^ (l31 & 7)) * 16;
            bf8_t kf = *(const bf8_t*)(Kb + l31 * 512 + sw);
            sa = __builtin_amdgcn_mfma_f32_32x32x16_bf16(kf, qf[ks], sa, 0, 0, 0);
        }
        __builtin_amdgcn_s_setprio(0);

#pragma unroll
        for (int s = 0; s < 2; ++s) {
            int b8 = s * 8;
            float p0 = fexp2(sa[b8 + 0]), p1 = fexp2(sa[b8 + 1]);
            float p2 = fexp2(sa[b8 + 2]), p3 = fexp2(sa[b8 + 3]);
            float p4 = fexp2(sa[b8 + 4]), p5 = fexp2(sa[b8 + 5]);
            float p6 = fexp2(sa[b8 + 6]), p7 = fexp2(sa[b8 + 7]);
            l_i += ((p0 + p1) + (p2 + p3)) + ((p4 + p5) + (p6 + p7));
            uint32_t w0 = cvtpk(p0, p1), w1 = cvtpk(p2, p3);
            uint32_t w2 = cvtpk(p4, p5), w3 = cvtpk(p6, p7);
            asm volatile("v_permlane32_swap_b32 %0, %1" : "+v"(w0), "+v"(w2));
            asm volatile("v_permlane32_swap_b32 %0, %1" : "+v"(w1), "+v"(w3));
            union { uint32_t u[4]; bf8_t v; } pa;
            pa.u[0] = w0; pa.u[1] = w1; pa.u[2] = w2; pa.u[3] = w3;

            __builtin_amdgcn_s_setprio(1);
#pragma unroll
            for (int nt = 0; nt < 8; ++nt) {
                int d = nt * 32 + l31;
                int ch = 2 * s + hi;
                bf8_t vf = *(const bf8_t*)(Vb + d * 64 + ((ch ^ ((d >> 2) & 3)) * 16));
                o[nt] = __builtin_amdgcn_mfma_f32_32x32x16_bf16(pa.v, vf, o[nt], 0, 0, 0);
            }
            __builtin_amdgcn_s_setprio(0);
        }

        if (it + 1 < 64) {
            asm volatile("s_waitcnt vmcnt(0)" ::: "memory");
            __builtin_amdgcn_s_barrier();
            __builtin_amdgcn_sched_barrier(0);
        }
    }

    float l_row = l_i + __shfl_xor(l_i, 32);
    ushort* op = Opart + (size_t)bid * (128 * 256) + (size_t)(wvi * 32) * 256;
#pragma unroll
    for (int nt = 0; nt < 8; ++nt) {
#pragma unroll
        for (int r = 0; r < 16; ++r) {
            int qrow = (r & 3) + 8 * (r >> 2) + 4 * hi;
            op[(size_t)qrow * 256 + nt * 32 + l31] = f2bf(o[nt][r]);
        }
    }
    if (lane < 32) {
        ml[(size_t)bid * 128 + wvi * 32 + l31] = l_row;
    }
}

// ---------------- fused combine + proj GEMM (LDS-staged combine, wave = 64r x 64c) ----------
__global__ __launch_bounds__(256) void projc_gemm(const ushort* __restrict__ Opart,
                                                  const float* __restrict__ ml,
                                                  const ushort* __restrict__ wT,
                                                  const float* __restrict__ bp,
                                                  const float* __restrict__ x,
                                                  float* __restrict__ outp) {
    __shared__ __align__(16) char sm[64 * 528];
    int t = threadIdx.x;
    int lane = t & 63, wvi = t >> 6;
    int lq = lane & 15, lg = lane >> 4;
    int nf0 = wvi * 4;                  // wave's 4 col-tiles (64 cols)
    int m0b = blockIdx.x * 64;          // block's 64 rows

    // ---- phase 1: combine the block's 64 rows once into LDS ----
    {
        int row = t >> 2, q4 = t & 3;
        int xrow = m0b + row;
        int batch = xrow >> 12, rr = xrow & 4095;
        int qt = rr >> 7, rit = rr & 127;
        int blkA = batch + 16 * qt, blkB = blkA + 8;
        float la = ml[(size_t)blkA * 128 + rit];
        float lb = ml[(size_t)blkB * 128 + rit];
        float inv = 1.0f / (la + lb);
        const ushort* Arow = Opart + (size_t)blkA * 32768 + (size_t)rit * 256;
        const ushort* Brow = Opart + (size_t)blkB * 32768 + (size_t)rit * 256;
        char* lrow = sm + row * 528;
#pragma unroll
        for (int i = 0; i < 8; ++i) {
            int c0 = q4 * 64 + i * 8;
            bf8_t fa = *(const bf8_t*)(Arow + c0);
            bf8_t fb = *(const bf8_t*)(Brow + c0);
            union { ushort u[8]; uint4 v; } pk;
#pragma unroll
            for (int j = 0; j < 8; ++j)
                pk.u[j] = f2bf((bf2f((ushort)fa[j]) + bf2f((ushort)fb[j])) * inv);
            *(uint4*)(lrow + c0 * 2) = pk.v;
        }
    }
    __syncthreads();

    // ---- phase 2: a[4][8] from LDS, proj GEMM (wave = 64 rows x 64 cols) ----
    bf8_t a[4][8];
#pragma unroll
    for (int tt = 0; tt < 4; ++tt)
#pragma unroll
        for (int ks = 0; ks < 8; ++ks)
            a[tt][ks] = *(const bf8_t*)(sm + (tt * 16 + lq) * 528 + (ks * 32 + lg * 8) * 2);

    f4_t acc[4][4];
#pragma unroll
    for (int tt = 0; tt < 4; ++tt)
#pragma unroll
        for (int i = 0; i < 4; ++i) acc[tt][i] = (f4_t)0.f;

    const ushort* brow = wT + (size_t)(nf0 * 16 + lq) * 256 + lg * 8;
#pragma unroll
    for (int nf = 0; nf < 4; ++nf) {
#pragma unroll
        for (int ks = 0; ks < 8; ++ks) {
            bf8_t bfr = *(const bf8_t*)(brow + nf * 16 * 256 + ks * 32);
            acc[0][nf] = __builtin_amdgcn_mfma_f32_16x16x32_bf16(a[0][ks], bfr, acc[0][nf], 0, 0, 0);
            acc[1][nf] = __builtin_amdgcn_mfma_f32_16x16x32_bf16(a[1][ks], bfr, acc[1][nf], 0, 0, 0);
            acc[2][nf] = __builtin_amdgcn_mfma_f32_16x16x32_bf16(a[2][ks], bfr, acc[2][nf], 0, 0, 0);
            acc[3][nf] = __builtin_amdgcn_mfma_f32_16x16x32_bf16(a[3][ks], bfr, acc[3][nf], 0, 0, 0);
        }
    }
#pragma unroll
    for (int tt = 0; tt < 4; ++tt) {
#pragma unroll
        for (int nf = 0; nf < 4; ++nf) {
            int col = (nf0 + nf) * 16 + lq;
            float bsv = bp[col];
#pragma unroll
            for (int r = 0; r < 4; ++r) {
                size_t idx = (size_t)(m0b + tt * 16 + lg * 4 + r) * 256 + col;
                outp[idx] = x[idx] + acc[tt][nf][r] + bsv;
            }
        }
    }
}

extern "C" void kernel_launch(void* const* d_in, const int* in_sizes, int n_in,
                              void* d_out, int out_size, void* d_ws, size_t ws_size,
                              hipStream_t stream) {
    const float* x  = (const float*)d_in[0];
    const float* gs = (const float*)d_in[1];
    const float* gb = (const float*)d_in[2];
    const float* wq = (const float*)d_in[3];
    const float* bq = (const float*)d_in[4];
    const float* wk = (const float*)d_in[5];
    const float* bk = (const float*)d_in[6];
    const float* wv = (const float*)d_in[7];
    const float* bv = (const float*)d_in[8];
    const float* wp = (const float*)d_in[9];
    const float* bp = (const float*)d_in[10];
    float* out = (float*)d_out;

    char* ws = (char*)d_ws;
    ushort* wT    = (ushort*)ws;                         // 512 KB
    float*  psum  = (float*)(ws + 512 * 1024);           // 64 KB
    float*  psumsq= (float*)(ws + 576 * 1024);           // 64 KB
    ushort* qb    = (ushort*)(ws + (size_t)17 * (1 << 20));
    ushort* kb    = (ushort*)(ws + (size_t)33 * (1 << 20));
    ushort* vTb   = (ushort*)(ws + (size_t)49 * (1 << 20));   // V transposed [b][d][hw]
    ushort* Opart = (ushort*)(ws + (size_t)65 * (1 << 20));   // 32 MB: 512 x 128 x 256 bf16
    float*  mlb   = (float*)(ws + (size_t)97 * (1 << 20));    // 256 KB: 512 x 128 float

    prep_kernel<<<768, 256, 0, stream>>>(x, psum, psumsq, wq, wk, wv, wp, wT);
    qkv_gn<<<512, 256, 0, stream>>>(x, psum, psumsq, gs, gb, wT, bq, bk, bv, qb, kb, vTb);

    hipFuncSetAttribute(reinterpret_cast<const void*>(flash_kernel),
                        hipFuncAttributeMaxDynamicSharedMemorySize, 65536);
    flash_kernel<<<512, 256, 65536, stream>>>(qb, kb, vTb, Opart, mlb);

    projc_gemm<<<512, 256, 0, stream>>>(Opart, mlb, wT + 3 * 65536, bp, x, out);
}